// Round 1
// baseline (6244.421 us; speedup 1.0000x reference)
//
#include <hip/hip_runtime.h>
#include <cstddef>

// Problem constants
#define Nn 32
#define Cc 128
#define Tt 128
#define Vv 25
#define HSs 3
#define TVe (Tt*Vv)            // 3200
#define BN_INV 0.9999950000374997f

// ---------------- workspace layout (floats) ----------------
// qk      : 0            .. 19,660,800   (N*192*T*V)
// att     : 19,660,800   .. 27,340,800   (N*3*T*V*V)
// s1/t1   : 27,340,800   .. 40,448,000   (N*C*T*V)
// sout/tout: 40,448,000  .. 53,555,200   (N*C*T*V)
// temporal reuse of qk region:
//   xbar @0 (524,288), qkt @524,288 (1,048,576), attT @1,572,864 (2,097,152),
//   tmp  @3,670,016 (13,107,200)  -> ends 16,777,216 < 19,660,800
// TCN: W2 (permuted tcn weights) @0 (114,688) — qk region dead by then
// total ws: 53,555,200 floats = 214.2 MB
#define OFF_QK    0u
#define OFF_ATT   19660800u
#define OFF_S1    27340800u
#define OFF_SOUT  40448000u
#define OFF_XBAR  0u
#define OFF_QKT   524288u
#define OFF_ATTT  1572864u
#define OFF_TMP   3670016u
#define OFF_W2    0u

// 1x1 conv: Y[n,o,t,v] = b[o] + sum_c W[o*ldw+c] * X[n,c,t,v]
__global__ void k_conv1x1(const float* __restrict__ X, const float* __restrict__ W,
                          const float* __restrict__ b, float* __restrict__ Y,
                          int O, int ldw) {
    int n = blockIdx.x / Tt, t = blockIdx.x % Tt;
    __shared__ float Xs[Cc*Vv];
    const float* xp = X + ((size_t)n*Cc*Tt + t)*Vv;
    for (int i = threadIdx.x; i < Cc*Vv; i += blockDim.x) {
        int c = i / Vv, v = i - (i/Vv)*Vv;
        Xs[i] = xp[(size_t)c*TVe + v];
    }
    __syncthreads();
    for (int i = threadIdx.x; i < O*Vv; i += blockDim.x) {
        int o = i / Vv, v = i - o*Vv;
        float acc = b ? b[o] : 0.f;
        const float* wr = W + (size_t)o*ldw;
        #pragma unroll 4
        for (int c = 0; c < Cc; ++c) acc += wr[c] * Xs[c*Vv + v];
        Y[(((size_t)n*O + o)*Tt + t)*Vv + v] = acc;
    }
}

// spatial attention: att[n,s,t,u,v] = att0[s,u,v] + tanh(sum_c q*k /32)*alpha[s]
__global__ void k_att_s(const float* __restrict__ qk, const float* __restrict__ att0,
                        const float* __restrict__ alphas, float* __restrict__ att) {
    int b = blockIdx.x;
    int n = b / (HSs*Tt); int rem = b - n*(HSs*Tt); int s = rem / Tt; int t = rem - s*Tt;
    __shared__ float qs[32*Vv], ks[32*Vv];
    const float* qp = qk + (((size_t)n*192 + s*32)*Tt + t)*Vv;
    const float* kp = qk + (((size_t)n*192 + 96 + s*32)*Tt + t)*Vv;
    for (int i = threadIdx.x; i < 32*Vv; i += blockDim.x) {
        int c = i / Vv, v = i - c*Vv;
        qs[i] = qp[(size_t)c*TVe + v];
        ks[i] = kp[(size_t)c*TVe + v];
    }
    __syncthreads();
    float alpha = alphas[s];
    for (int i = threadIdx.x; i < Vv*Vv; i += blockDim.x) {
        int u = i / Vv, v = i - u*Vv;
        float acc = 0.f;
        #pragma unroll
        for (int c = 0; c < 32; ++c) acc += qs[c*Vv+u] * ks[c*Vv+v];
        att[(((size_t)(n*HSs + s)*Tt + t)*Vv*Vv) + i] =
            att0[s*Vv*Vv + i] + tanhf(acc * (1.f/32.f)) * alpha;
    }
}

// fused spatial einsum + out-conv + bn + residual + lrelu
// s1[n,o,t,v] = lrelu( x + bn( b[o] + sum_{s,c} W[o,s*128+c] * (sum_u x[n,c,t,u]*att[n,s,t,u,v]) ) )
__global__ void k_spatial_out(const float* __restrict__ X, const float* __restrict__ att,
                              const float* __restrict__ W, const float* __restrict__ b,
                              const float* __restrict__ g, const float* __restrict__ be,
                              float* __restrict__ Y) {
    int n = blockIdx.x / Tt, t = blockIdx.x % Tt;
    __shared__ float Xs[Cc*Vv];        // 3200
    __shared__ float As[HSs*Vv*Vv];    // 1875
    __shared__ float Bs[HSs*Cc*Vv];    // 9600
    const float* xp = X + ((size_t)n*Cc*Tt + t)*Vv;
    for (int i = threadIdx.x; i < Cc*Vv; i += blockDim.x) {
        int c = i / Vv, v = i - c*Vv;
        Xs[i] = xp[(size_t)c*TVe + v];
    }
    for (int i = threadIdx.x; i < HSs*Vv*Vv; i += blockDim.x) {
        int s = i / (Vv*Vv); int uv = i - s*(Vv*Vv);
        As[i] = att[(((size_t)(n*HSs + s)*Tt + t)*Vv*Vv) + uv];
    }
    __syncthreads();
    for (int i = threadIdx.x; i < HSs*Cc*Vv; i += blockDim.x) {
        int s = i / (Cc*Vv); int cv = i - s*(Cc*Vv); int c = cv / Vv, v = cv - (cv/Vv)*Vv;
        float acc = 0.f;
        const float* arow = As + s*Vv*Vv + v;
        const float* xrow = Xs + c*Vv;
        #pragma unroll
        for (int u = 0; u < Vv; ++u) acc += xrow[u] * arow[u*Vv];
        Bs[i] = acc;
    }
    __syncthreads();
    for (int i = threadIdx.x; i < Cc*Vv; i += blockDim.x) {
        int o = i / Vv, v = i - o*Vv;
        float acc = b[o];
        const float* wr = W + (size_t)o*(HSs*Cc);
        #pragma unroll 4
        for (int sc = 0; sc < HSs*Cc; ++sc) acc += wr[sc] * Bs[sc*Vv + v];
        float y = acc * (g[o]*BN_INV) + be[o];
        float r = Xs[i] + y;   // Xs[o*25+v] == x[n,o,t,v]
        Y[(((size_t)n*Cc + o)*Tt + t)*Vv + v] = r > 0.f ? r : 0.1f*r;
    }
}

// FFN: Y = lrelu(Res + bn(W@In + b))   (128x128 conv1x1)
__global__ void k_ffn(const float* __restrict__ In, const float* __restrict__ Res,
                      const float* __restrict__ W, const float* __restrict__ b,
                      const float* __restrict__ g, const float* __restrict__ be,
                      float* __restrict__ Y) {
    int n = blockIdx.x / Tt, t = blockIdx.x % Tt;
    __shared__ float Is[Cc*Vv];
    const float* ip = In + ((size_t)n*Cc*Tt + t)*Vv;
    for (int i = threadIdx.x; i < Cc*Vv; i += blockDim.x) {
        int c = i / Vv, v = i - c*Vv;
        Is[i] = ip[(size_t)c*TVe + v];
    }
    __syncthreads();
    for (int i = threadIdx.x; i < Cc*Vv; i += blockDim.x) {
        int o = i / Vv, v = i - o*Vv;
        float acc = b[o];
        const float* wr = W + o*Cc;
        #pragma unroll 4
        for (int c = 0; c < Cc; ++c) acc += wr[c] * Is[c*Vv + v];
        float y = acc * (g[o]*BN_INV) + be[o];
        size_t oidx = (((size_t)n*Cc + o)*Tt + t)*Vv + v;
        float r = Res[oidx] + y;
        Y[oidx] = r > 0.f ? r : 0.1f*r;
    }
}

// xbar[n,c,t] = mean_v s_out[n,c,t,v]
__global__ void k_mean_v(const float* __restrict__ X, float* __restrict__ xbar) {
    int idx = blockIdx.x*blockDim.x + threadIdx.x;
    if (idx >= Nn*Cc*Tt) return;
    const float* p = X + (size_t)idx*Vv;
    float s = 0.f;
    #pragma unroll
    for (int v = 0; v < Vv; ++v) s += p[v];
    xbar[idx] = s * (1.f/25.f);
}

// qkt[n,oc,t] = b[oc] + sum_c W[oc*128+c]*xbar[n,c,t]   (O=256)
__global__ void k_lin_t(const float* __restrict__ xbar, const float* __restrict__ W,
                        const float* __restrict__ b, float* __restrict__ Y) {
    int idx = blockIdx.x*blockDim.x + threadIdx.x;
    if (idx >= Nn*256*Tt) return;
    int t = idx % Tt; int no = idx / Tt; int o = no % 256; int n = no / 256;
    float acc = b[o];
    const float* wr = W + o*Cc;
    const float* xp = xbar + (size_t)n*Cc*Tt + t;
    #pragma unroll 4
    for (int c = 0; c < Cc; ++c) acc += wr[c] * xp[c*Tt];
    Y[idx] = acc;
}

// temporal attention, stored TRANSPOSED: attT[n,h,u,t] = mask*alpha*tanh(dot/32)
__global__ void k_att_t(const float* __restrict__ qkt, const float* __restrict__ af,
                        const float* __restrict__ ab, float* __restrict__ attT) {
    int n = blockIdx.x / 4, h = blockIdx.x % 4;
    __shared__ float qs[32*Tt], ks[32*Tt];
    const float* qp = qkt + ((size_t)n*256 + h*32)*Tt;
    const float* kp = qkt + ((size_t)n*256 + 128 + h*32)*Tt;
    for (int i = threadIdx.x; i < 32*Tt; i += blockDim.x) { qs[i] = qp[i]; ks[i] = kp[i]; }
    __syncthreads();
    float alpha = (h < 2) ? af[h] : ab[h-2];
    for (int i = threadIdx.x; i < Tt*Tt; i += blockDim.x) {
        int t = i / Tt, u = i - t*Tt;
        bool keep = (h < 2) ? (t >= u) : (t <= u);
        float val = 0.f;
        if (keep) {
            float acc = 0.f;
            #pragma unroll
            for (int c = 0; c < 32; ++c) acc += qs[c*Tt + t] * ks[c*Tt + u];
            val = tanhf(acc * (1.f/32.f)) * alpha;
        }
        attT[(((size_t)(n*4 + h)*Tt + u)*Tt) + t] = val;
    }
}

// temporal einsum accumulate: acc[n,o,u,v] (+)= sum_t tmp[n,o,t,v]*attT[n,s,u,t]
// on last head: out = lrelu(res + bn(acc))
__global__ void k_tein(const float* __restrict__ tmp, const float* __restrict__ attT,
                       int s, int first, int last,
                       const float* __restrict__ b, const float* __restrict__ g,
                       const float* __restrict__ be, const float* __restrict__ res,
                       float* __restrict__ acc, float* __restrict__ out) {
    int n = blockIdx.x / Cc, o = blockIdx.x % Cc;
    __shared__ float Ts[Tt*Vv];
    const float* tp = tmp + ((size_t)n*Cc + o)*TVe;
    for (int i = threadIdx.x; i < TVe; i += blockDim.x) Ts[i] = tp[i];
    __syncthreads();
    const float* ar = attT + ((size_t)(n*4 + s))*Tt*Tt;
    for (int i = threadIdx.x; i < TVe; i += blockDim.x) {
        int u = i / Vv, v = i - u*Vv;
        size_t oidx = ((size_t)n*Cc + o)*TVe + i;
        float a = first ? b[o] : acc[oidx];
        const float* arow = ar + (size_t)u*Tt;
        int tlo = (s < 2) ? u : 0;        // forward mask: nonzero t>=u ; backward: t<=u
        int thi = (s < 2) ? Tt : u+1;
        for (int t = tlo; t < thi; ++t) a += Ts[t*Vv + v] * arow[t];
        if (last) {
            float y = a * (g[o]*BN_INV) + be[o];
            float r = res[oidx] + y;
            out[oidx] = r > 0.f ? r : 0.1f*r;
        } else {
            acc[oidx] = a;
        }
    }
}

// permute tcn weights (C,C,7,1) -> W2[k][o][c]
__global__ void k_wperm(const float* __restrict__ W, float* __restrict__ W2) {
    int idx = blockIdx.x*blockDim.x + threadIdx.x;
    if (idx >= Cc*Cc*7) return;
    int k = idx / (Cc*Cc); int oc = idx - k*(Cc*Cc);
    int o = oc / Cc, c = oc - o*Cc;
    W2[idx] = W[((size_t)o*Cc + c)*7 + k];
}

// TCN 7x1 over T + bn + residual + lrelu -> d_out
__global__ void k_tcn(const float* __restrict__ X, const float* __restrict__ W2,
                      const float* __restrict__ b, const float* __restrict__ g,
                      const float* __restrict__ be, float* __restrict__ out) {
    int n = blockIdx.x / Tt, t = blockIdx.x % Tt;
    __shared__ float Xs[Cc*Vv];
    float acc[13];
    float resv[13];
    int cnt = 0;
    for (int i = threadIdx.x; i < Cc*Vv; i += blockDim.x) { acc[cnt++] = b[i/Vv]; }
    for (int k = 0; k < 7; ++k) {
        int tt = t + k - 3;
        __syncthreads();
        const float* xp = X + ((size_t)n*Cc*Tt + tt)*Vv;
        bool ok = (tt >= 0 && tt < Tt);
        for (int i = threadIdx.x; i < Cc*Vv; i += blockDim.x) {
            int c = i / Vv, v = i - c*Vv;
            Xs[i] = ok ? xp[(size_t)c*TVe + v] : 0.f;
        }
        __syncthreads();
        int j = 0;
        for (int i = threadIdx.x; i < Cc*Vv; i += blockDim.x, ++j) {
            int o = i / Vv, v = i - o*Vv;
            float a = acc[j];
            const float* wr = W2 + ((size_t)k*Cc + o)*Cc;
            #pragma unroll 4
            for (int c = 0; c < Cc; ++c) a += wr[c] * Xs[c*Vv + v];
            acc[j] = a;
            if (k == 3) resv[j] = Xs[i];
        }
    }
    int j = 0;
    for (int i = threadIdx.x; i < Cc*Vv; i += blockDim.x, ++j) {
        int o = i / Vv, v = i - o*Vv;
        float y = acc[j] * (g[o]*BN_INV) + be[o];
        float r = resv[j] + y;
        out[(((size_t)n*Cc + o)*Tt + t)*Vv + v] = r > 0.f ? r : 0.1f*r;
    }
}

extern "C" void kernel_launch(void* const* d_in, const int* in_sizes, int n_in,
                              void* d_out, int out_size, void* d_ws, size_t ws_size,
                              hipStream_t stream) {
    const float* x       = (const float*)d_in[0];
    const float* w_in_s  = (const float*)d_in[1];
    const float* b_in_s  = (const float*)d_in[2];
    const float* att0s   = (const float*)d_in[3];
    const float* alphas  = (const float*)d_in[4];
    const float* w_out_s = (const float*)d_in[5];
    const float* b_out_s = (const float*)d_in[6];
    const float* g_out_s = (const float*)d_in[7];
    const float* be_out_s= (const float*)d_in[8];
    const float* w_ff_s  = (const float*)d_in[9];
    const float* b_ff_s  = (const float*)d_in[10];
    const float* g_ff_s  = (const float*)d_in[11];
    const float* be_ff_s = (const float*)d_in[12];
    const float* w_in_t  = (const float*)d_in[13];
    const float* b_in_t  = (const float*)d_in[14];
    const float* alphat_f= (const float*)d_in[15];
    const float* alphat_b= (const float*)d_in[16];
    const float* w_out_t = (const float*)d_in[17];
    const float* b_out_t = (const float*)d_in[18];
    const float* g_out_t = (const float*)d_in[19];
    const float* be_out_t= (const float*)d_in[20];
    const float* w_ff_t  = (const float*)d_in[21];
    const float* b_ff_t  = (const float*)d_in[22];
    const float* g_ff_t  = (const float*)d_in[23];
    const float* be_ff_t = (const float*)d_in[24];
    const float* w_tcn   = (const float*)d_in[25];
    const float* b_tcn   = (const float*)d_in[26];
    const float* g_tcn   = (const float*)d_in[27];
    const float* be_tcn  = (const float*)d_in[28];

    float* ws   = (float*)d_ws;
    float* qk   = ws + OFF_QK;
    float* att  = ws + OFF_ATT;
    float* s1   = ws + OFF_S1;     // also t1
    float* sout = ws + OFF_SOUT;   // also t_out (in-place)
    float* xbar = ws + OFF_XBAR;
    float* qkt  = ws + OFF_QKT;
    float* attT = ws + OFF_ATTT;
    float* tmp  = ws + OFF_TMP;
    float* w2   = ws + OFF_W2;
    float* out  = (float*)d_out;

    dim3 blk(256);
    int NT = Nn*Tt;           // 4096

    // ---- spatial branch ----
    k_conv1x1<<<NT, blk, 0, stream>>>(x, w_in_s, b_in_s, qk, 192, Cc);
    k_att_s<<<Nn*HSs*Tt, blk, 0, stream>>>(qk, att0s, alphas, att);
    k_spatial_out<<<NT, blk, 0, stream>>>(x, att, w_out_s, b_out_s, g_out_s, be_out_s, s1);
    k_ffn<<<NT, blk, 0, stream>>>(s1, x, w_ff_s, b_ff_s, g_ff_s, be_ff_s, sout);

    // ---- temporal branch ----
    k_mean_v<<<(Nn*Cc*Tt + 255)/256, blk, 0, stream>>>(sout, xbar);
    k_lin_t<<<(Nn*256*Tt + 255)/256, blk, 0, stream>>>(xbar, w_in_t, b_in_t, qkt);
    k_att_t<<<Nn*4, blk, 0, stream>>>(qkt, alphat_f, alphat_b, attT);
    for (int s = 0; s < 4; ++s) {
        // tmp = W_s @ sout  (row o of w_out_t, offset s*128, ld=1024)
        k_conv1x1<<<NT, blk, 0, stream>>>(sout, w_out_t + s*Cc, nullptr, tmp, Cc, 4*Cc);
        k_tein<<<Nn*Cc, blk, 0, stream>>>(tmp, attT, s, (s==0)?1:0, (s==3)?1:0,
                                          b_out_t, g_out_t, be_out_t, sout, s1, s1);
    }
    // s1 now holds t1 = lrelu(sout + bn(temporal conv))
    k_ffn<<<NT, blk, 0, stream>>>(s1, sout, w_ff_t, b_ff_t, g_ff_t, be_ff_t, sout); // in-place t_out

    // ---- TCN + final ----
    k_wperm<<<(Cc*Cc*7 + 255)/256, blk, 0, stream>>>(w_tcn, w2);
    k_tcn<<<NT, blk, 0, stream>>>(sout, w2, b_tcn, g_tcn, be_tcn, out);
}

// Round 2
// 2160.888 us; speedup vs baseline: 2.8897x; 2.8897x over previous
//
#include <hip/hip_runtime.h>
#include <cstddef>

#define Nn 32
#define Cc 128
#define Tt 128
#define Vv 25
#define HSs 3
#define TVe (Tt*Vv)            // 3200
#define BN_INV 0.9999950000374997f

// ---------------- workspace layout (floats), total 53,555,200 = 214.2 MB ----
// region [0 .. 19,660,800)          : qk  (192*3200*32)   [spatial attn input]
//   reused: y2buf [0..13,107,200)   : einsum head output
//   reused (temporal): xbar@0(524288), qkt@524288(1,048,576),
//                      attb@1,572,864(2,097,152), w2@3,670,016(114,688)
// region [13,107,200 .. 26,214,400) : sout (tail of qk region + att region)
// region [19,660,800 .. 27,340,800) : att_s (3*625*128*32) [dead before sout written]
// region [27,340,800 .. 40,448,000) : sacc -> tmp -> tout
// region [40,448,000 .. 53,555,200) : s1 -> tacc -> t1 (in-place)
#define OFF_QK    0u
#define OFF_Y2    0u
#define OFF_XBAR  0u
#define OFF_QKT   524288u
#define OFF_ATTB  1572864u
#define OFF_W2    3670016u
#define OFF_SOUT  13107200u
#define OFF_ATTS  19660800u
#define OFF_SACC  27340800u
#define OFF_S1    40448000u

// =====================================================================
// Generic register-blocked GEMM: D[n] = epilogue( A @ B[n] )
// Tile: 128(M) x 64(N), 256 threads, 8x4 micro-tile, K-block 16.
// BMODE 0: B row-major [K][ldb] per n (also A row-major [M][lda], shared)
// BMODE 1: TCN shifted B: k=(kidx,c), B[k][j] = Bn[c*3200 + j + (kidx-3)*25]
// BMODE 2: tein: A[m=(o,v)][k=t] = An[o*3200 + k*25 + v]; B=att [t][u]
// DMODE 0: D[m][j] at m*ldd + j      DMODE 1: D at o*3200 + j*25 + v
// epilogue: val = acc (+bias[o]) (+prev[addr]); if(gg): bn+res+lrelu
// maskmode: 0 none; 1 forward (k >= j0); 2 backward (k < j0+64)
// =====================================================================
template<int BMODE, int DMODE>
__global__ __launch_bounds__(256, 2) void gemm_k(
    const float* __restrict__ A, const float* __restrict__ B,
    float* __restrict__ D, const float* __restrict__ prevp,
    const float* __restrict__ resp, const float* __restrict__ bias,
    const float* __restrict__ gg, const float* __restrict__ bb,
    int M, int K, int lda, int ldb, int ldd,
    long an_stride, long bn_stride, long dn_stride,
    int gn, int maskmode)
{
    __shared__ float As[16*128];
    __shared__ float Bs[16*64];

    const int n  = blockIdx.y;
    const int mt = blockIdx.x / gn;
    const int nt = blockIdx.x - mt*gn;
    const int m0 = mt*128;
    const int j0 = nt*64;

    const float* An = A + (size_t)n * an_stride;
    const float* Bn = B + (size_t)n * bn_stride;

    const int tid = threadIdx.x;
    const int tx = tid & 15, ty = tid >> 4;

    // A-stage thread mapping
    const int am  = tid >> 1;            // 0..127
    const int ak8 = (tid & 1) * 8;       // 0 or 8
    // precompute strided-A decomposition (BMODE 2)
    int ao = 0, av_ = 0;
    if (BMODE == 2) { int mg = m0 + am; ao = mg / 25; av_ = mg - ao*25; }
    // B-stage thread mapping
    const int bk  = tid >> 4;            // 0..15
    const int bj4 = (tid & 15) * 4;

    float acc[8][4];
    #pragma unroll
    for (int i = 0; i < 8; ++i)
        #pragma unroll
        for (int j = 0; j < 4; ++j) acc[i][j] = 0.f;

    int kbeg = (maskmode == 1) ? j0 : 0;
    int kend = (maskmode == 2) ? (j0 + 64) : K;

    for (int k0 = kbeg; k0 < kend; k0 += 16) {
        // ---- fetch A fragment to registers ----
        float areg[8];
        if (BMODE == 2) {
            const float* ap = An + (size_t)ao*3200 + (size_t)(k0 + ak8)*25 + av_;
            #pragma unroll
            for (int i = 0; i < 8; ++i) areg[i] = ap[i*25];
        } else {
            int mg = m0 + am;
            if (mg < M) {
                const float* ap = A + (size_t)mg*lda + k0 + ak8;
                float4 x0 = *(const float4*)ap;
                float4 x1 = *(const float4*)(ap + 4);
                areg[0]=x0.x; areg[1]=x0.y; areg[2]=x0.z; areg[3]=x0.w;
                areg[4]=x1.x; areg[5]=x1.y; areg[6]=x1.z; areg[7]=x1.w;
            } else {
                #pragma unroll
                for (int i = 0; i < 8; ++i) areg[i] = 0.f;
            }
        }
        // ---- fetch B fragment ----
        float4 breg;
        if (BMODE == 0) {
            breg = *(const float4*)(Bn + (size_t)(k0 + bk)*ldb + j0 + bj4);
        } else if (BMODE == 1) {
            int kg = k0 + bk;
            int kidx = kg >> 7, c = kg & 127;
            int base = j0 + bj4 + (kidx - 3)*25;
            float t[4];
            #pragma unroll
            for (int i = 0; i < 4; ++i) {
                int e = base + i;
                t[i] = ((unsigned)e < 3200u) ? Bn[(size_t)c*3200 + e] : 0.f;
            }
            breg.x=t[0]; breg.y=t[1]; breg.z=t[2]; breg.w=t[3];
        } else {
            breg = *(const float4*)(Bn + (size_t)(k0 + bk)*128 + j0 + bj4);
        }

        __syncthreads();   // previous tile consumed
        #pragma unroll
        for (int i = 0; i < 8; ++i) As[(ak8 + i)*128 + am] = areg[i];
        *(float4*)(Bs + bk*64 + bj4) = breg;
        __syncthreads();   // staging visible

        // ---- inner product ----
        #pragma unroll
        for (int kk = 0; kk < 16; ++kk) {
            float4 b4 = *(const float4*)(Bs + kk*64 + tx*4);
            float4 a0 = *(const float4*)(As + kk*128 + ty*8);
            float4 a1 = *(const float4*)(As + kk*128 + ty*8 + 4);
            float a[8] = {a0.x,a0.y,a0.z,a0.w,a1.x,a1.y,a1.z,a1.w};
            float bv[4] = {b4.x,b4.y,b4.z,b4.w};
            #pragma unroll
            for (int i = 0; i < 8; ++i)
                #pragma unroll
                for (int j = 0; j < 4; ++j)
                    acc[i][j] += a[i]*bv[j];
        }
    }

    // ---- epilogue ----
    #pragma unroll
    for (int i = 0; i < 8; ++i) {
        int mg = m0 + ty*8 + i;
        if (DMODE == 0 && mg >= M) break;
        int o, v = 0;
        if (DMODE == 1) { o = mg / 25; v = mg - o*25; }
        else o = mg;
        float bi = bias ? bias[o] : 0.f;
        float gv = 0.f, bv2 = 0.f;
        if (gg) { gv = gg[o]*BN_INV; bv2 = bb[o]; }
        #pragma unroll
        for (int j = 0; j < 4; ++j) {
            int col = j0 + tx*4 + j;
            size_t addr = (DMODE == 1)
                ? ((size_t)o*3200 + (size_t)col*25 + v)
                : ((size_t)mg*ldd + col);
            addr += (size_t)n * dn_stride;
            float val = acc[i][j] + bi;
            if (prevp) val += prevp[addr];
            if (gg) {
                val = val*gv + bv2;
                val += resp[addr];
                val = val > 0.f ? val : 0.1f*val;
            }
            D[addr] = val;
        }
    }
}

// spatial attention: att[n,s,t,u,v] = att0[s,u,v] + tanh(qk/32)*alpha
__global__ void k_att_s(const float* __restrict__ qk, const float* __restrict__ att0,
                        const float* __restrict__ alphas, float* __restrict__ att) {
    int b = blockIdx.x;
    int n = b / (HSs*Tt); int rem = b - n*(HSs*Tt); int s = rem / Tt; int t = rem - s*Tt;
    __shared__ float qs[32*Vv], ks[32*Vv];
    const float* qp = qk + (((size_t)n*192 + s*32)*Tt + t)*Vv;
    const float* kp = qk + (((size_t)n*192 + 96 + s*32)*Tt + t)*Vv;
    for (int i = threadIdx.x; i < 32*Vv; i += blockDim.x) {
        int c = i / Vv, v = i - c*Vv;
        qs[i] = qp[(size_t)c*TVe + v];
        ks[i] = kp[(size_t)c*TVe + v];
    }
    __syncthreads();
    float alpha = alphas[s];
    for (int i = threadIdx.x; i < Vv*Vv; i += blockDim.x) {
        int u = i / Vv, v = i - u*Vv;
        float acc = 0.f;
        #pragma unroll
        for (int c = 0; c < 32; ++c) acc += qs[c*Vv+u] * ks[c*Vv+v];
        att[(((size_t)(n*HSs + s)*Tt + t)*Vv*Vv) + i] =
            att0[s*Vv*Vv + i] + tanhf(acc * (1.f/32.f)) * alpha;
    }
}

// spatial einsum head s: y2[n,c,t,v] = sum_u x[n,c,t,u]*att[n,s,t,u,v]
__global__ void k_eins(const float* __restrict__ X, const float* __restrict__ att,
                       int s, float* __restrict__ y2) {
    int n = blockIdx.x / Tt, t = blockIdx.x % Tt;
    __shared__ float Xs[Cc*Vv];     // [c][u]
    __shared__ float AsT[Vv*Vv];    // [v][u]
    const float* xp = X + ((size_t)n*Cc*Tt + t)*Vv;
    for (int i = threadIdx.x; i < Cc*Vv; i += blockDim.x) {
        int c = i / Vv, u = i - c*Vv;
        Xs[i] = xp[(size_t)c*TVe + u];
    }
    const float* ap = att + (((size_t)(n*HSs + s)*Tt + t)*Vv*Vv);
    for (int i = threadIdx.x; i < Vv*Vv; i += blockDim.x) {
        int u = i / Vv, v = i - u*Vv;
        AsT[v*Vv + u] = ap[i];
    }
    __syncthreads();
    for (int i = threadIdx.x; i < 32*Vv; i += blockDim.x) {
        int cg = i & 31, v = i >> 5;
        const float* xq = Xs + cg*4*Vv;
        const float* aq = AsT + v*Vv;
        float a0=0,a1=0,a2=0,a3=0;
        #pragma unroll
        for (int u = 0; u < Vv; ++u) {
            float avv = aq[u];
            a0 += xq[u]*avv; a1 += xq[Vv+u]*avv;
            a2 += xq[2*Vv+u]*avv; a3 += xq[3*Vv+u]*avv;
        }
        float* yp = y2 + (size_t)n*(Cc*TVe) + (size_t)(cg*4)*TVe + t*Vv + v;
        yp[0] = a0; yp[TVe] = a1; yp[2*TVe] = a2; yp[3*TVe] = a3;
    }
}

// xbar[n,c,t] = mean_v sout[n,c,t,v]
__global__ void k_mean_v(const float* __restrict__ X, float* __restrict__ xbar) {
    int idx = blockIdx.x*blockDim.x + threadIdx.x;
    if (idx >= Nn*Cc*Tt) return;
    const float* p = X + (size_t)idx*Vv;
    float s = 0.f;
    #pragma unroll
    for (int v = 0; v < Vv; ++v) s += p[v];
    xbar[idx] = s * (1.f/25.f);
}

// temporal attention: attb[n,h,t,u] = mask * alpha * tanh(dot/32)
__global__ void k_att_t(const float* __restrict__ qkt, const float* __restrict__ af,
                        const float* __restrict__ ab, float* __restrict__ attb) {
    int n = blockIdx.x >> 2, h = blockIdx.x & 3;
    __shared__ float qs[32*Tt], ks[32*Tt];
    const float* qp = qkt + ((size_t)n*256 + h*32)*Tt;
    const float* kp = qkt + ((size_t)n*256 + 128 + h*32)*Tt;
    for (int i = threadIdx.x; i < 32*Tt; i += blockDim.x) { qs[i] = qp[i]; ks[i] = kp[i]; }
    __syncthreads();
    float alpha = (h < 2) ? af[h] : ab[h-2];
    for (int i = threadIdx.x; i < Tt*Tt; i += blockDim.x) {
        int t = i >> 7, u = i & 127;
        bool keep = (h < 2) ? (t >= u) : (t <= u);
        float val = 0.f;
        if (keep) {
            float acc = 0.f;
            #pragma unroll
            for (int c = 0; c < 32; ++c) acc += qs[c*Tt + t] * ks[c*Tt + u];
            val = tanhf(acc * (1.f/32.f)) * alpha;
        }
        attb[((size_t)(n*4 + h) << 14) + i] = val;
    }
}

// permute tcn weights (C,C,7,1) -> W2[o][kidx*128+c]
__global__ void k_wperm(const float* __restrict__ W, float* __restrict__ W2) {
    int idx = blockIdx.x*blockDim.x + threadIdx.x;
    if (idx >= Cc*Cc*7) return;
    int o = idx / (7*Cc); int r = idx - o*(7*Cc);
    int k = r / Cc, c = r - k*Cc;
    W2[idx] = W[((size_t)o*Cc + c)*7 + k];
}

extern "C" void kernel_launch(void* const* d_in, const int* in_sizes, int n_in,
                              void* d_out, int out_size, void* d_ws, size_t ws_size,
                              hipStream_t stream) {
    const float* x       = (const float*)d_in[0];
    const float* w_in_s  = (const float*)d_in[1];
    const float* b_in_s  = (const float*)d_in[2];
    const float* att0s   = (const float*)d_in[3];
    const float* alphas  = (const float*)d_in[4];
    const float* w_out_s = (const float*)d_in[5];
    const float* b_out_s = (const float*)d_in[6];
    const float* g_out_s = (const float*)d_in[7];
    const float* be_out_s= (const float*)d_in[8];
    const float* w_ff_s  = (const float*)d_in[9];
    const float* b_ff_s  = (const float*)d_in[10];
    const float* g_ff_s  = (const float*)d_in[11];
    const float* be_ff_s = (const float*)d_in[12];
    const float* w_in_t  = (const float*)d_in[13];
    const float* b_in_t  = (const float*)d_in[14];
    const float* alphat_f= (const float*)d_in[15];
    const float* alphat_b= (const float*)d_in[16];
    const float* w_out_t = (const float*)d_in[17];
    const float* b_out_t = (const float*)d_in[18];
    const float* g_out_t = (const float*)d_in[19];
    const float* be_out_t= (const float*)d_in[20];
    const float* w_ff_t  = (const float*)d_in[21];
    const float* b_ff_t  = (const float*)d_in[22];
    const float* g_ff_t  = (const float*)d_in[23];
    const float* be_ff_t = (const float*)d_in[24];
    const float* w_tcn   = (const float*)d_in[25];
    const float* b_tcn   = (const float*)d_in[26];
    const float* g_tcn   = (const float*)d_in[27];
    const float* be_tcn  = (const float*)d_in[28];

    float* ws   = (float*)d_ws;
    float* qk   = ws + OFF_QK;
    float* y2   = ws + OFF_Y2;
    float* xbar = ws + OFF_XBAR;
    float* qkt  = ws + OFF_QKT;
    float* attb = ws + OFF_ATTB;
    float* w2   = ws + OFF_W2;
    float* sout = ws + OFF_SOUT;
    float* atts = ws + OFF_ATTS;
    float* sacc = ws + OFF_SACC;   // -> tmp -> tout
    float* s1   = ws + OFF_S1;     // -> tacc -> t1 (in-place)
    float* out  = (float*)d_out;

    dim3 blk(256);
    const long SV = 409600;        // n-stride for [n][128][3200] buffers
    const float* NUL = nullptr;

    // ---- spatial branch ----
    // qk = W_in_s @ x + b   (M=192,K=128,N=3200)
    gemm_k<0,0><<<dim3(2*50, Nn), blk, 0, stream>>>(
        w_in_s, x, qk, NUL, NUL, b_in_s, NUL, NUL,
        192, 128, 128, 3200, 3200, 0, SV, (long)192*3200, 50, 0);
    k_att_s<<<Nn*HSs*Tt, blk, 0, stream>>>(qk, att0s, alphas, atts);
    for (int s = 0; s < HSs; ++s) {
        k_eins<<<Nn*Tt, blk, 0, stream>>>(x, atts, s, y2);
        // sacc (+)= W_s @ y2 ; last head: s1 = lrelu(x + bn(sacc))
        gemm_k<0,0><<<dim3(50, Nn), blk, 0, stream>>>(
            w_out_s + s*Cc, y2, (s == 2) ? s1 : sacc,
            (s > 0) ? sacc : NUL, (s == 2) ? x : NUL,
            (s == 0) ? b_out_s : NUL,
            (s == 2) ? g_out_s : NUL, be_out_s,
            128, 128, 384, 3200, 3200, 0, SV, SV, 50, 0);
    }
    // sout = lrelu(x + bn(W_ff_s @ s1 + b))
    gemm_k<0,0><<<dim3(50, Nn), blk, 0, stream>>>(
        w_ff_s, s1, sout, NUL, x, b_ff_s, g_ff_s, be_ff_s,
        128, 128, 128, 3200, 3200, 0, SV, SV, 50, 0);

    // ---- temporal branch ----
    k_mean_v<<<(Nn*Cc*Tt + 255)/256, blk, 0, stream>>>(sout, xbar);
    // qkt = W_in_t @ xbar + b   (M=256,K=128,N=128 per n)
    gemm_k<0,0><<<dim3(2*2, Nn), blk, 0, stream>>>(
        w_in_t, xbar, qkt, NUL, NUL, b_in_t, NUL, NUL,
        256, 128, 128, 128, 128, 0, (long)Cc*Tt, (long)256*Tt, 2, 0);
    k_att_t<<<Nn*4, blk, 0, stream>>>(qkt, alphat_f, alphat_b, attb);
    for (int h = 0; h < 4; ++h) {
        // tmp = W_h @ sout
        gemm_k<0,0><<<dim3(50, Nn), blk, 0, stream>>>(
            w_out_t + h*Cc, sout, sacc, NUL, NUL, NUL, NUL, NUL,
            128, 128, 512, 3200, 3200, 0, SV, SV, 50, 0);
        // tacc (+)= tmp @ att_h ; last head: t1 = lrelu(sout + bn(tacc)) in-place
        gemm_k<2,1><<<dim3(50, Nn), blk, 0, stream>>>(
            sacc, attb + (size_t)h*Tt*Tt, s1,
            (h > 0) ? s1 : NUL, (h == 3) ? sout : NUL,
            (h == 0) ? b_out_t : NUL,
            (h == 3) ? g_out_t : NUL, be_out_t,
            3200, 128, 0, 128, 0, SV, (long)4*Tt*Tt, SV, 2, (h < 2) ? 1 : 2);
    }
    // tout = lrelu(sout + bn(W_ff_t @ t1 + b))  -> sacc region
    gemm_k<0,0><<<dim3(50, Nn), blk, 0, stream>>>(
        w_ff_t, s1, sacc, NUL, sout, b_ff_t, g_ff_t, be_ff_t,
        128, 128, 128, 3200, 3200, 0, SV, SV, 50, 0);

    // ---- TCN + final ----
    k_wperm<<<(Cc*Cc*7 + 255)/256, blk, 0, stream>>>(w_tcn, w2);
    // out = lrelu(tout + bn(conv7(tout) + b))   (K = 7*128 = 896, shifted B)
    gemm_k<1,0><<<dim3(50, Nn), blk, 0, stream>>>(
        w2, sacc, out, NUL, sacc, b_tcn, g_tcn, be_tcn,
        128, 896, 896, 3200, 3200, 0, SV, SV, 50, 0);
}

// Round 3
// 1640.698 us; speedup vs baseline: 3.8060x; 1.3171x over previous
//
#include <hip/hip_runtime.h>
#include <cstddef>

#define Nn 32
#define Cc 128
#define Tt 128
#define Vv 25
#define HSs 3
#define TVe (Tt*Vv)            // 3200
#define BN_INV 0.9999950000374997f

// ---------------- workspace layout (floats), total 53,555,200 = 214.2 MB ----
// region [0 .. 19,660,800)          : qk  (192*3200*32)
//   reused: y2buf [0..13,107,200)   : einsum head output
//   reused (temporal): xbar@0(524288), qkt@524288(1,048,576),
//                      attb@1,572,864(2,097,152), w2@3,670,016(114,688)
// region [13,107,200 .. 26,214,400) : sout
// region [19,660,800 .. 27,340,800) : att_s (dead before sout written)
// region [27,340,800 .. 40,448,000) : sacc -> tmp -> tout
// region [40,448,000 .. 53,555,200) : s1 -> tacc -> t1 (in-place)
#define OFF_QK    0u
#define OFF_Y2    0u
#define OFF_XBAR  0u
#define OFF_QKT   524288u
#define OFF_ATTB  1572864u
#define OFF_W2    3670016u
#define OFF_SOUT  13107200u
#define OFF_ATTS  19660800u
#define OFF_SACC  27340800u
#define OFF_S1    40448000u

// =====================================================================
// Generic register-blocked GEMM: D[n] = epilogue( A @ B[n] )
// Tile: 128(M) x 64(N), 256 threads, 8x4 micro-tile, K-block 16.
// BMODE 0: B row-major [K][ldb] per n
// BMODE 1: TCN shifted B: k=(kidx,c), B[k][j] = Bn[c*3200 + j + (kidx-3)*25]
// BMODE 3: tein B: col=(c,v), B[k=t][col] = Bn[c*3200 + t*25 + v]
// A: row-major [M][lda] at An = A + n*an_stride (an_stride=0 for weights)
// DMODE 0: D[m][col] at m*ldd + col (float4)
// DMODE 2: m=u, col=(c,v): D at c*3200 + u*25 + v (float4 when no v-wrap)
// epilogue: val = acc (+bias[o]) (+prev[addr]); if(gg): bn+res+lrelu
// =====================================================================
template<int BMODE, int DMODE>
__global__ __launch_bounds__(256, 2) void gemm_k(
    const float* __restrict__ A, const float* __restrict__ B,
    float* __restrict__ D, const float* __restrict__ prevp,
    const float* __restrict__ resp, const float* __restrict__ bias,
    const float* __restrict__ gg, const float* __restrict__ bb,
    int M, int K, int lda, int ldb, int ldd,
    long an_stride, long bn_stride, long dn_stride, int gn)
{
    __shared__ float As[16*128];
    __shared__ float Bs[16*64];

    const int n  = blockIdx.y;
    const int mt = blockIdx.x / gn;
    const int nt = blockIdx.x - mt*gn;
    const int m0 = mt*128;
    const int j0 = nt*64;

    const float* An = A + (size_t)n * an_stride;
    const float* Bn = B + (size_t)n * bn_stride;

    const int tid = threadIdx.x;
    const int tx = tid & 15, ty = tid >> 4;

    const int am  = tid >> 1;            // 0..127
    const int ak8 = (tid & 1) * 8;       // 0 or 8
    const int bk  = tid >> 4;            // 0..15
    const int bj4 = (tid & 15) * 4;

    // BMODE 3: precompute (c,v) per fetched column
    int bc[4], bv[4];
    if (BMODE == 3) {
        #pragma unroll
        for (int i = 0; i < 4; ++i) {
            int col = j0 + bj4 + i;
            bc[i] = col / 25; bv[i] = col - 25*bc[i];
        }
    }

    float acc[8][4];
    #pragma unroll
    for (int i = 0; i < 8; ++i)
        #pragma unroll
        for (int j = 0; j < 4; ++j) acc[i][j] = 0.f;

    for (int k0 = 0; k0 < K; k0 += 16) {
        // ---- fetch A fragment ----
        float areg[8];
        {
            int mg = m0 + am;
            if (mg < M) {
                const float* ap = An + (size_t)mg*lda + k0 + ak8;
                float4 x0 = *(const float4*)ap;
                float4 x1 = *(const float4*)(ap + 4);
                areg[0]=x0.x; areg[1]=x0.y; areg[2]=x0.z; areg[3]=x0.w;
                areg[4]=x1.x; areg[5]=x1.y; areg[6]=x1.z; areg[7]=x1.w;
            } else {
                #pragma unroll
                for (int i = 0; i < 8; ++i) areg[i] = 0.f;
            }
        }
        // ---- fetch B fragment ----
        float breg[4];
        if (BMODE == 0) {
            float4 t4 = *(const float4*)(Bn + (size_t)(k0 + bk)*ldb + j0 + bj4);
            breg[0]=t4.x; breg[1]=t4.y; breg[2]=t4.z; breg[3]=t4.w;
        } else if (BMODE == 1) {
            int kg = k0 + bk;
            int kidx = kg >> 7, c = kg & 127;
            int base = j0 + bj4 + (kidx - 3)*25;
            #pragma unroll
            for (int i = 0; i < 4; ++i) {
                int e = base + i;
                breg[i] = ((unsigned)e < 3200u) ? Bn[(size_t)c*3200 + e] : 0.f;
            }
        } else { // BMODE 3
            int kg = k0 + bk;
            #pragma unroll
            for (int i = 0; i < 4; ++i)
                breg[i] = Bn[(size_t)bc[i]*3200 + kg*25 + bv[i]];
        }

        __syncthreads();
        #pragma unroll
        for (int i = 0; i < 8; ++i) As[(ak8 + i)*128 + am] = areg[i];
        *(float4*)(Bs + bk*64 + bj4) = breg[0] == breg[0] ?
            (float4){breg[0],breg[1],breg[2],breg[3]} :
            (float4){breg[0],breg[1],breg[2],breg[3]};
        __syncthreads();

        // ---- inner product ----
        #pragma unroll
        for (int kk = 0; kk < 16; ++kk) {
            float4 b4 = *(const float4*)(Bs + kk*64 + tx*4);
            float4 a0 = *(const float4*)(As + kk*128 + ty*8);
            float4 a1 = *(const float4*)(As + kk*128 + ty*8 + 4);
            float a[8] = {a0.x,a0.y,a0.z,a0.w,a1.x,a1.y,a1.z,a1.w};
            float bvv[4] = {b4.x,b4.y,b4.z,b4.w};
            #pragma unroll
            for (int i = 0; i < 8; ++i)
                #pragma unroll
                for (int j = 0; j < 4; ++j)
                    acc[i][j] += a[i]*bvv[j];
        }
    }

    // ---- epilogue ----
    if (DMODE == 0) {
        const int col = j0 + tx*4;
        #pragma unroll
        for (int i = 0; i < 8; ++i) {
            int mg = m0 + ty*8 + i;
            if (mg >= M) break;
            float bi = bias ? bias[mg] : 0.f;
            size_t addr = (size_t)mg*ldd + col + (size_t)n*dn_stride;
            float4 val = {acc[i][0]+bi, acc[i][1]+bi, acc[i][2]+bi, acc[i][3]+bi};
            if (prevp) {
                float4 p = *(const float4*)(prevp + addr);
                val.x += p.x; val.y += p.y; val.z += p.z; val.w += p.w;
            }
            if (gg) {
                float gv = gg[mg]*BN_INV, b2 = bb[mg];
                float4 r = *(const float4*)(resp + addr);
                val.x = val.x*gv + b2 + r.x; val.y = val.y*gv + b2 + r.y;
                val.z = val.z*gv + b2 + r.z; val.w = val.w*gv + b2 + r.w;
                val.x = val.x > 0.f ? val.x : 0.1f*val.x;
                val.y = val.y > 0.f ? val.y : 0.1f*val.y;
                val.z = val.z > 0.f ? val.z : 0.1f*val.z;
                val.w = val.w > 0.f ? val.w : 0.1f*val.w;
            }
            *(float4*)(D + addr) = val;
        }
    } else { // DMODE 2
        const int col0 = j0 + tx*4;
        const int c0 = col0 / 25, v0 = col0 - 25*c0;
        if (v0 <= 21) {
            float bi = bias ? bias[c0] : 0.f;
            float gv = 0.f, b2 = 0.f;
            if (gg) { gv = gg[c0]*BN_INV; b2 = bb[c0]; }
            #pragma unroll
            for (int i = 0; i < 8; ++i) {
                int u = m0 + ty*8 + i;
                size_t addr = (size_t)c0*3200 + (size_t)u*25 + v0 + (size_t)n*dn_stride;
                float4 val = {acc[i][0]+bi, acc[i][1]+bi, acc[i][2]+bi, acc[i][3]+bi};
                if (prevp) {
                    float4 p = *(const float4*)(prevp + addr);
                    val.x += p.x; val.y += p.y; val.z += p.z; val.w += p.w;
                }
                if (gg) {
                    float4 r = *(const float4*)(resp + addr);
                    val.x = val.x*gv + b2 + r.x; val.y = val.y*gv + b2 + r.y;
                    val.z = val.z*gv + b2 + r.z; val.w = val.w*gv + b2 + r.w;
                    val.x = val.x > 0.f ? val.x : 0.1f*val.x;
                    val.y = val.y > 0.f ? val.y : 0.1f*val.y;
                    val.z = val.z > 0.f ? val.z : 0.1f*val.z;
                    val.w = val.w > 0.f ? val.w : 0.1f*val.w;
                }
                *(float4*)(D + addr) = val;
            }
        } else {
            #pragma unroll
            for (int i = 0; i < 8; ++i) {
                int u = m0 + ty*8 + i;
                #pragma unroll
                for (int j = 0; j < 4; ++j) {
                    int col = col0 + j;
                    int c = col / 25, v = col - 25*c;
                    size_t addr = (size_t)c*3200 + (size_t)u*25 + v + (size_t)n*dn_stride;
                    float val = acc[i][j] + (bias ? bias[c] : 0.f);
                    if (prevp) val += prevp[addr];
                    if (gg) {
                        val = val*(gg[c]*BN_INV) + bb[c] + resp[addr];
                        val = val > 0.f ? val : 0.1f*val;
                    }
                    D[addr] = val;
                }
            }
        }
    }
}

// spatial attention: att[n,s,t,u,v] = att0[s,u,v] + tanh(qk/32)*alpha
__global__ void k_att_s(const float* __restrict__ qk, const float* __restrict__ att0,
                        const float* __restrict__ alphas, float* __restrict__ att) {
    int b = blockIdx.x;
    int n = b / (HSs*Tt); int rem = b - n*(HSs*Tt); int s = rem / Tt; int t = rem - s*Tt;
    __shared__ float qs[32*Vv], ks[32*Vv];
    const float* qp = qk + (((size_t)n*192 + s*32)*Tt + t)*Vv;
    const float* kp = qk + (((size_t)n*192 + 96 + s*32)*Tt + t)*Vv;
    for (int i = threadIdx.x; i < 32*Vv; i += blockDim.x) {
        int c = i / Vv, v = i - c*Vv;
        qs[i] = qp[(size_t)c*TVe + v];
        ks[i] = kp[(size_t)c*TVe + v];
    }
    __syncthreads();
    float alpha = alphas[s];
    for (int i = threadIdx.x; i < Vv*Vv; i += blockDim.x) {
        int u = i / Vv, v = i - u*Vv;
        float acc = 0.f;
        #pragma unroll
        for (int c = 0; c < 32; ++c) acc += qs[c*Vv+u] * ks[c*Vv+v];
        att[(((size_t)(n*HSs + s)*Tt + t)*Vv*Vv) + i] =
            att0[s*Vv*Vv + i] + tanhf(acc * (1.f/32.f)) * alpha;
    }
}

// spatial einsum head s: y2[n,c,t,v] = sum_u x[n,c,t,u]*att[n,s,t,u,v]
__global__ void k_eins(const float* __restrict__ X, const float* __restrict__ att,
                       int s, float* __restrict__ y2) {
    int n = blockIdx.x / Tt, t = blockIdx.x % Tt;
    __shared__ float Xs[Cc*Vv];     // [c][u]
    __shared__ float AsT[Vv*Vv];    // [v][u]
    const float* xp = X + ((size_t)n*Cc*Tt + t)*Vv;
    for (int i = threadIdx.x; i < Cc*Vv; i += blockDim.x) {
        int c = i / Vv, u = i - c*Vv;
        Xs[i] = xp[(size_t)c*TVe + u];
    }
    const float* ap = att + (((size_t)(n*HSs + s)*Tt + t)*Vv*Vv);
    for (int i = threadIdx.x; i < Vv*Vv; i += blockDim.x) {
        int u = i / Vv, v = i - u*Vv;
        AsT[v*Vv + u] = ap[i];
    }
    __syncthreads();
    for (int i = threadIdx.x; i < 32*Vv; i += blockDim.x) {
        int cg = i & 31, v = i >> 5;
        const float* xq = Xs + cg*4*Vv;
        const float* aq = AsT + v*Vv;
        float a0=0,a1=0,a2=0,a3=0;
        #pragma unroll
        for (int u = 0; u < Vv; ++u) {
            float avv = aq[u];
            a0 += xq[u]*avv; a1 += xq[Vv+u]*avv;
            a2 += xq[2*Vv+u]*avv; a3 += xq[3*Vv+u]*avv;
        }
        float* yp = y2 + (size_t)n*(Cc*TVe) + (size_t)(cg*4)*TVe + t*Vv + v;
        yp[0] = a0; yp[TVe] = a1; yp[2*TVe] = a2; yp[3*TVe] = a3;
    }
}

// xbar[n,c,t] = mean_v sout[n,c,t,v]
__global__ void k_mean_v(const float* __restrict__ X, float* __restrict__ xbar) {
    int idx = blockIdx.x*blockDim.x + threadIdx.x;
    if (idx >= Nn*Cc*Tt) return;
    const float* p = X + (size_t)idx*Vv;
    float s = 0.f;
    #pragma unroll
    for (int v = 0; v < Vv; ++v) s += p[v];
    xbar[idx] = s * (1.f/25.f);
}

// temporal attention, stored TRANSPOSED: attb[n,h,u,t] = mask*alpha*tanh(dot/32)
__global__ void k_att_t(const float* __restrict__ qkt, const float* __restrict__ af,
                        const float* __restrict__ ab, float* __restrict__ attb) {
    int n = blockIdx.x >> 2, h = blockIdx.x & 3;
    __shared__ float qs[32*Tt], ks[32*Tt];
    const float* qp = qkt + ((size_t)n*256 + h*32)*Tt;
    const float* kp = qkt + ((size_t)n*256 + 128 + h*32)*Tt;
    for (int i = threadIdx.x; i < 32*Tt; i += blockDim.x) { qs[i] = qp[i]; ks[i] = kp[i]; }
    __syncthreads();
    float alpha = (h < 2) ? af[h] : ab[h-2];
    for (int i = threadIdx.x; i < Tt*Tt; i += blockDim.x) {
        int u = i >> 7, t = i & 127;       // write [u][t] coalesced
        bool keep = (h < 2) ? (t >= u) : (t <= u);
        float val = 0.f;
        if (keep) {
            float acc = 0.f;
            #pragma unroll
            for (int c = 0; c < 32; ++c) acc += qs[c*Tt + t] * ks[c*Tt + u];
            val = tanhf(acc * (1.f/32.f)) * alpha;
        }
        attb[((size_t)(n*4 + h) << 14) + i] = val;
    }
}

// permute tcn weights (C,C,7,1) -> W2[o][kidx*128+c]
__global__ void k_wperm(const float* __restrict__ W, float* __restrict__ W2) {
    int idx = blockIdx.x*blockDim.x + threadIdx.x;
    if (idx >= Cc*Cc*7) return;
    int o = idx / (7*Cc); int r = idx - o*(7*Cc);
    int k = r / Cc, c = r - k*Cc;
    W2[idx] = W[((size_t)o*Cc + c)*7 + k];
}

extern "C" void kernel_launch(void* const* d_in, const int* in_sizes, int n_in,
                              void* d_out, int out_size, void* d_ws, size_t ws_size,
                              hipStream_t stream) {
    const float* x       = (const float*)d_in[0];
    const float* w_in_s  = (const float*)d_in[1];
    const float* b_in_s  = (const float*)d_in[2];
    const float* att0s   = (const float*)d_in[3];
    const float* alphas  = (const float*)d_in[4];
    const float* w_out_s = (const float*)d_in[5];
    const float* b_out_s = (const float*)d_in[6];
    const float* g_out_s = (const float*)d_in[7];
    const float* be_out_s= (const float*)d_in[8];
    const float* w_ff_s  = (const float*)d_in[9];
    const float* b_ff_s  = (const float*)d_in[10];
    const float* g_ff_s  = (const float*)d_in[11];
    const float* be_ff_s = (const float*)d_in[12];
    const float* w_in_t  = (const float*)d_in[13];
    const float* b_in_t  = (const float*)d_in[14];
    const float* alphat_f= (const float*)d_in[15];
    const float* alphat_b= (const float*)d_in[16];
    const float* w_out_t = (const float*)d_in[17];
    const float* b_out_t = (const float*)d_in[18];
    const float* g_out_t = (const float*)d_in[19];
    const float* be_out_t= (const float*)d_in[20];
    const float* w_ff_t  = (const float*)d_in[21];
    const float* b_ff_t  = (const float*)d_in[22];
    const float* g_ff_t  = (const float*)d_in[23];
    const float* be_ff_t = (const float*)d_in[24];
    const float* w_tcn   = (const float*)d_in[25];
    const float* b_tcn   = (const float*)d_in[26];
    const float* g_tcn   = (const float*)d_in[27];
    const float* be_tcn  = (const float*)d_in[28];

    float* ws   = (float*)d_ws;
    float* qk   = ws + OFF_QK;
    float* y2   = ws + OFF_Y2;
    float* xbar = ws + OFF_XBAR;
    float* qkt  = ws + OFF_QKT;
    float* attb = ws + OFF_ATTB;
    float* w2   = ws + OFF_W2;
    float* sout = ws + OFF_SOUT;
    float* atts = ws + OFF_ATTS;
    float* sacc = ws + OFF_SACC;   // -> tmp -> tout
    float* s1   = ws + OFF_S1;     // -> tacc -> t1 (in-place)
    float* out  = (float*)d_out;

    dim3 blk(256);
    const long SV = 409600;        // n-stride for [n][128][3200] buffers
    const float* NUL = nullptr;

    // ---- spatial branch ----
    gemm_k<0,0><<<dim3(2*50, Nn), blk, 0, stream>>>(
        w_in_s, x, qk, NUL, NUL, b_in_s, NUL, NUL,
        192, 128, 128, 3200, 3200, 0, SV, (long)192*3200, 50);
    k_att_s<<<Nn*HSs*Tt, blk, 0, stream>>>(qk, att0s, alphas, atts);
    for (int s = 0; s < HSs; ++s) {
        k_eins<<<Nn*Tt, blk, 0, stream>>>(x, atts, s, y2);
        gemm_k<0,0><<<dim3(50, Nn), blk, 0, stream>>>(
            w_out_s + s*Cc, y2, (s == 2) ? s1 : sacc,
            (s > 0) ? sacc : NUL, (s == 2) ? x : NUL,
            (s == 0) ? b_out_s : NUL,
            (s == 2) ? g_out_s : NUL, be_out_s,
            128, 128, 384, 3200, 3200, 0, SV, SV, 50);
    }
    gemm_k<0,0><<<dim3(50, Nn), blk, 0, stream>>>(
        w_ff_s, s1, sout, NUL, x, b_ff_s, g_ff_s, be_ff_s,
        128, 128, 128, 3200, 3200, 0, SV, SV, 50);

    // ---- temporal branch ----
    k_mean_v<<<(Nn*Cc*Tt + 255)/256, blk, 0, stream>>>(sout, xbar);
    gemm_k<0,0><<<dim3(2*2, Nn), blk, 0, stream>>>(
        w_in_t, xbar, qkt, NUL, NUL, b_in_t, NUL, NUL,
        256, 128, 128, 128, 128, 0, (long)Cc*Tt, (long)256*Tt, 2);
    k_att_t<<<Nn*4, blk, 0, stream>>>(qkt, alphat_f, alphat_b, attb);
    for (int h = 0; h < 4; ++h) {
        // tmp = W_h @ sout
        gemm_k<0,0><<<dim3(50, Nn), blk, 0, stream>>>(
            w_out_t + h*Cc, sout, sacc, NUL, NUL, NUL, NUL, NUL,
            128, 128, 512, 3200, 3200, 0, SV, SV, 50);
        // tacc (+)= att_h^T-rows: D[u? -> stored [c][u*25+v]] ; last: bn+res+lrelu
        gemm_k<3,2><<<dim3(50, Nn), blk, 0, stream>>>(
            attb + (size_t)h*Tt*Tt, sacc, s1,
            (h > 0) ? s1 : NUL, (h == 3) ? sout : NUL,
            (h == 0) ? b_out_t : NUL,
            (h == 3) ? g_out_t : NUL, be_out_t,
            128, 128, 128, 0, 0, (long)4*Tt*Tt, SV, SV, 50);
    }
    // tout = lrelu(sout + bn(W_ff_t @ t1 + b))  -> sacc region
    gemm_k<0,0><<<dim3(50, Nn), blk, 0, stream>>>(
        w_ff_t, s1, sacc, NUL, sout, b_ff_t, g_ff_t, be_ff_t,
        128, 128, 128, 3200, 3200, 0, SV, SV, 50);

    // ---- TCN + final ----
    k_wperm<<<(Cc*Cc*7 + 255)/256, blk, 0, stream>>>(w_tcn, w2);
    gemm_k<1,0><<<dim3(50, Nn), blk, 0, stream>>>(
        w2, sacc, out, NUL, sacc, b_tcn, g_tcn, be_tcn,
        128, 896, 896, 3200, 3200, 0, SV, SV, 50);
}

// Round 4
// 1122.424 us; speedup vs baseline: 5.5633x; 1.4617x over previous
//
#include <hip/hip_runtime.h>
#include <cstddef>

#define Nn 32
#define Cc 128
#define Tt 128
#define Vv 25
#define HSs 3
#define TVe (Tt*Vv)            // 3200
#define BN_INV 0.9999950000374997f

// ---------------- workspace layout (floats), total 53,555,200 = 214.2 MB ----
#define OFF_QK    0u
#define OFF_Y2    0u
#define OFF_XBAR  0u
#define OFF_QKT   524288u
#define OFF_ATTB  1572864u
#define OFF_W2    3670016u
#define OFF_SOUT  13107200u
#define OFF_ATTS  19660800u
#define OFF_SACC  27340800u
#define OFF_S1    40448000u

typedef __attribute__((ext_vector_type(8))) short bf16x8;
typedef __attribute__((ext_vector_type(4))) float f32x4;

__device__ __forceinline__ short f2bf(float f) {
    union { float f; unsigned u; } x; x.f = f;
    unsigned r = (x.u + 0x7FFFu + ((x.u >> 16) & 1u)) >> 16;
    return (short)r;
}

// =====================================================================
// MFMA bf16 GEMM: D[n] = epilogue( A @ B[n] ), fp32 in/out, bf16 compute.
// Tile: 128(M) x 64(N), 256 threads = 4 waves, K-block 32.
// Wave w computes m-tiles {2w,2w+1} (32 rows) x all 4 col-tiles (64 cols)
// via 8x mfma_f32_16x16x32_bf16 per K-block.
// LDS fragment-linear: slot(lane)=16B of 8 k-contiguous bf16.
//   A-frag: lane = (m&15) + 16*(k>>3)    (A[m][k], k within K-block)
//   B-frag: lane = (col&15) + 16*(k>>3)  (B[k][col])
// BMODE 0: B row-major [K][ldb];  BMODE 1: TCN shifted rows (k=(kidx,c));
// BMODE 3: tein B[k=t][(c,v)] = Bn[c*3200 + t*25 + v]
// DMODE 0: D[m][col] @ m*ldd+col;  DMODE 2: D @ c*3200 + u*25 + v (m=u)
// epilogue: val = acc (+bias) (+prev); if(gg): bn + res + lrelu
// =====================================================================
template<int BMODE, int DMODE>
__global__ __launch_bounds__(256, 2) void gemm_k(
    const float* __restrict__ A, const float* __restrict__ B,
    float* __restrict__ D, const float* __restrict__ prevp,
    const float* __restrict__ resp, const float* __restrict__ bias,
    const float* __restrict__ gg, const float* __restrict__ bb,
    int M, int K, int lda, int ldb, int ldd,
    long an_stride, long bn_stride, long dn_stride, int gn)
{
    __shared__ short Al[8*64*8];   // 8 m-tiles x 64 lane-slots x 8 bf16 = 8KB
    __shared__ short Bl[4*64*8];   // 4 c-tiles x 64 lane-slots x 8 bf16 = 4KB

    const int n  = blockIdx.y;
    const int mt = blockIdx.x / gn;
    const int nt = blockIdx.x - mt*gn;
    const int m0 = mt*128;
    const int j0 = nt*64;

    const float* An = A + (size_t)n * an_stride;
    const float* Bn = B + (size_t)n * bn_stride;

    const int tid  = threadIdx.x;
    const int wav  = tid >> 6;
    const int lane = tid & 63;
    const int lq   = lane >> 4;      // quad
    const int l16  = lane & 15;

    // A staging: thread -> (row sm, k-half skh: 16 floats)
    const int sm  = tid >> 1;
    const int skh = tid & 1;
    // B staging: thread -> (col scol, k-quad squad: 8 floats)
    const int scol  = tid & 63;
    const int squad = tid >> 6;

    int bcc = 0, bvv = 0;
    if (BMODE == 3) { int col = j0 + scol; bcc = col/25; bvv = col - 25*bcc; }

    f32x4 acc[2][4];
    #pragma unroll
    for (int i = 0; i < 2; ++i)
        #pragma unroll
        for (int c = 0; c < 4; ++c) acc[i][c] = (f32x4){0.f,0.f,0.f,0.f};

    for (int k0 = 0; k0 < K; k0 += 32) {
        // ---- global fetch A: 16 fp32 (row sm, k-range skh*16..+15) ----
        float af[16];
        {
            int mg = m0 + sm;
            if (mg < M) {
                const float* ap = An + (size_t)mg*lda + k0 + skh*16;
                float4 q0 = *(const float4*)(ap);
                float4 q1 = *(const float4*)(ap+4);
                float4 q2 = *(const float4*)(ap+8);
                float4 q3 = *(const float4*)(ap+12);
                af[0]=q0.x; af[1]=q0.y; af[2]=q0.z; af[3]=q0.w;
                af[4]=q1.x; af[5]=q1.y; af[6]=q1.z; af[7]=q1.w;
                af[8]=q2.x; af[9]=q2.y; af[10]=q2.z; af[11]=q2.w;
                af[12]=q3.x; af[13]=q3.y; af[14]=q3.z; af[15]=q3.w;
            } else {
                #pragma unroll
                for (int i = 0; i < 16; ++i) af[i] = 0.f;
            }
        }
        // ---- global fetch B: 8 fp32 (k = squad*8+j, col scol) ----
        float bfv[8];
        #pragma unroll
        for (int j = 0; j < 8; ++j) {
            int kg = k0 + squad*8 + j;
            if (BMODE == 0) {
                bfv[j] = Bn[(size_t)kg*ldb + j0 + scol];
            } else if (BMODE == 1) {
                int kidx = kg >> 7, c = kg & 127;
                int e = j0 + scol + (kidx - 3)*25;
                bfv[j] = ((unsigned)e < 3200u) ? Bn[(size_t)c*3200 + e] : 0.f;
            } else { // BMODE 3
                bfv[j] = Bn[(size_t)bcc*3200 + (size_t)kg*25 + bvv];
            }
        }

        __syncthreads();   // previous tile consumed
        // ---- stage A (two quads) ----
        {
            short* Ap = Al + ((size_t)((sm>>4)*64 + (sm&15) + 32*skh))*8;
            bf16x8 p0, p1;
            #pragma unroll
            for (int i = 0; i < 8; ++i) { p0[i] = f2bf(af[i]); p1[i] = f2bf(af[8+i]); }
            *(bf16x8*)Ap = p0;
            *(bf16x8*)(Ap + 16*8) = p1;   // next quad = +16 lane-slots
        }
        // ---- stage B ----
        {
            short* Bp = Bl + ((size_t)((scol>>4)*64 + (scol&15) + 16*squad))*8;
            bf16x8 p;
            #pragma unroll
            for (int i = 0; i < 8; ++i) p[i] = f2bf(bfv[i]);
            *(bf16x8*)Bp = p;
        }
        __syncthreads();

        // ---- MFMA ----
        bf16x8 afr[2], bfr[4];
        #pragma unroll
        for (int i = 0; i < 2; ++i)
            afr[i] = *(const bf16x8*)(Al + ((size_t)((2*wav+i)*64 + lane))*8);
        #pragma unroll
        for (int c = 0; c < 4; ++c)
            bfr[c] = *(const bf16x8*)(Bl + ((size_t)(c*64 + lane))*8);
        #pragma unroll
        for (int i = 0; i < 2; ++i)
            #pragma unroll
            for (int c = 0; c < 4; ++c)
                acc[i][c] = __builtin_amdgcn_mfma_f32_16x16x32_bf16(
                    afr[i], bfr[c], acc[i][c], 0, 0, 0);
    }

    // ---- epilogue: row = m0 + (2w+i)*16 + lq*4 + r ; col = j0 + ct*16 + l16 ----
    #pragma unroll
    for (int i = 0; i < 2; ++i) {
        const int mbase = m0 + (2*wav + i)*16 + lq*4;
        #pragma unroll
        for (int ct = 0; ct < 4; ++ct) {
            const int col = j0 + ct*16 + l16;
            if (DMODE == 0) {
                #pragma unroll
                for (int r = 0; r < 4; ++r) {
                    int mg = mbase + r;
                    if (mg < M) {
                        size_t addr = (size_t)mg*ldd + col + (size_t)n*dn_stride;
                        float val = acc[i][ct][r] + (bias ? bias[mg] : 0.f);
                        if (prevp) val += prevp[addr];
                        if (gg) {
                            val = val*(gg[mg]*BN_INV) + bb[mg] + resp[addr];
                            val = val > 0.f ? val : 0.1f*val;
                        }
                        D[addr] = val;
                    }
                }
            } else { // DMODE 2: m=u, col=(c,v)
                int c = col/25, v = col - 25*c;
                float bi = bias ? bias[c] : 0.f;
                float gv = 0.f, b2 = 0.f;
                if (gg) { gv = gg[c]*BN_INV; b2 = bb[c]; }
                #pragma unroll
                for (int r = 0; r < 4; ++r) {
                    int u = mbase + r;
                    size_t addr = (size_t)c*3200 + (size_t)u*25 + v + (size_t)n*dn_stride;
                    float val = acc[i][ct][r] + bi;
                    if (prevp) val += prevp[addr];
                    if (gg) {
                        val = val*gv + b2 + resp[addr];
                        val = val > 0.f ? val : 0.1f*val;
                    }
                    D[addr] = val;
                }
            }
        }
    }
}

// spatial attention: att[n,s,t,u,v] = att0[s,u,v] + tanh(qk/32)*alpha
__global__ void k_att_s(const float* __restrict__ qk, const float* __restrict__ att0,
                        const float* __restrict__ alphas, float* __restrict__ att) {
    int b = blockIdx.x;
    int n = b / (HSs*Tt); int rem = b - n*(HSs*Tt); int s = rem / Tt; int t = rem - s*Tt;
    __shared__ float qs[32*Vv], ks[32*Vv];
    const float* qp = qk + (((size_t)n*192 + s*32)*Tt + t)*Vv;
    const float* kp = qk + (((size_t)n*192 + 96 + s*32)*Tt + t)*Vv;
    for (int i = threadIdx.x; i < 32*Vv; i += blockDim.x) {
        int c = i / Vv, v = i - c*Vv;
        qs[i] = qp[(size_t)c*TVe + v];
        ks[i] = kp[(size_t)c*TVe + v];
    }
    __syncthreads();
    float alpha = alphas[s];
    for (int i = threadIdx.x; i < Vv*Vv; i += blockDim.x) {
        int u = i / Vv, v = i - u*Vv;
        float acc = 0.f;
        #pragma unroll
        for (int c = 0; c < 32; ++c) acc += qs[c*Vv+u] * ks[c*Vv+v];
        att[(((size_t)(n*HSs + s)*Tt + t)*Vv*Vv) + i] =
            att0[s*Vv*Vv + i] + tanhf(acc * (1.f/32.f)) * alpha;
    }
}

// spatial einsum head s: y2[n,c,t,v] = sum_u x[n,c,t,u]*att[n,s,t,u,v]
__global__ void k_eins(const float* __restrict__ X, const float* __restrict__ att,
                       int s, float* __restrict__ y2) {
    int n = blockIdx.x / Tt, t = blockIdx.x % Tt;
    __shared__ float Xs[Cc*Vv];     // [c][u]
    __shared__ float AsT[Vv*Vv];    // [v][u]
    const float* xp = X + ((size_t)n*Cc*Tt + t)*Vv;
    for (int i = threadIdx.x; i < Cc*Vv; i += blockDim.x) {
        int c = i / Vv, u = i - c*Vv;
        Xs[i] = xp[(size_t)c*TVe + u];
    }
    const float* ap = att + (((size_t)(n*HSs + s)*Tt + t)*Vv*Vv);
    for (int i = threadIdx.x; i < Vv*Vv; i += blockDim.x) {
        int u = i / Vv, v = i - u*Vv;
        AsT[v*Vv + u] = ap[i];
    }
    __syncthreads();
    for (int i = threadIdx.x; i < 32*Vv; i += blockDim.x) {
        int cg = i & 31, v = i >> 5;
        const float* xq = Xs + cg*4*Vv;
        const float* aq = AsT + v*Vv;
        float a0=0,a1=0,a2=0,a3=0;
        #pragma unroll
        for (int u = 0; u < Vv; ++u) {
            float avv = aq[u];
            a0 += xq[u]*avv; a1 += xq[Vv+u]*avv;
            a2 += xq[2*Vv+u]*avv; a3 += xq[3*Vv+u]*avv;
        }
        float* yp = y2 + (size_t)n*(Cc*TVe) + (size_t)(cg*4)*TVe + t*Vv + v;
        yp[0] = a0; yp[TVe] = a1; yp[2*TVe] = a2; yp[3*TVe] = a3;
    }
}

// xbar[n,c,t] = mean_v sout[n,c,t,v]
__global__ void k_mean_v(const float* __restrict__ X, float* __restrict__ xbar) {
    int idx = blockIdx.x*blockDim.x + threadIdx.x;
    if (idx >= Nn*Cc*Tt) return;
    const float* p = X + (size_t)idx*Vv;
    float s = 0.f;
    #pragma unroll
    for (int v = 0; v < Vv; ++v) s += p[v];
    xbar[idx] = s * (1.f/25.f);
}

// temporal attention, stored TRANSPOSED: attb[n,h,u,t] = mask*alpha*tanh(dot/32)
__global__ void k_att_t(const float* __restrict__ qkt, const float* __restrict__ af,
                        const float* __restrict__ ab, float* __restrict__ attb) {
    int n = blockIdx.x >> 2, h = blockIdx.x & 3;
    __shared__ float qs[32*Tt], ks[32*Tt];
    const float* qp = qkt + ((size_t)n*256 + h*32)*Tt;
    const float* kp = qkt + ((size_t)n*256 + 128 + h*32)*Tt;
    for (int i = threadIdx.x; i < 32*Tt; i += blockDim.x) { qs[i] = qp[i]; ks[i] = kp[i]; }
    __syncthreads();
    float alpha = (h < 2) ? af[h] : ab[h-2];
    for (int i = threadIdx.x; i < Tt*Tt; i += blockDim.x) {
        int u = i >> 7, t = i & 127;       // write [u][t] coalesced
        bool keep = (h < 2) ? (t >= u) : (t <= u);
        float val = 0.f;
        if (keep) {
            float acc = 0.f;
            #pragma unroll
            for (int c = 0; c < 32; ++c) acc += qs[c*Tt + t] * ks[c*Tt + u];
            val = tanhf(acc * (1.f/32.f)) * alpha;
        }
        attb[((size_t)(n*4 + h) << 14) + i] = val;
    }
}

// permute tcn weights (C,C,7,1) -> W2[o][kidx*128+c]
__global__ void k_wperm(const float* __restrict__ W, float* __restrict__ W2) {
    int idx = blockIdx.x*blockDim.x + threadIdx.x;
    if (idx >= Cc*Cc*7) return;
    int o = idx / (7*Cc); int r = idx - o*(7*Cc);
    int k = r / Cc, c = r - k*Cc;
    W2[idx] = W[((size_t)o*Cc + c)*7 + k];
}

extern "C" void kernel_launch(void* const* d_in, const int* in_sizes, int n_in,
                              void* d_out, int out_size, void* d_ws, size_t ws_size,
                              hipStream_t stream) {
    const float* x       = (const float*)d_in[0];
    const float* w_in_s  = (const float*)d_in[1];
    const float* b_in_s  = (const float*)d_in[2];
    const float* att0s   = (const float*)d_in[3];
    const float* alphas  = (const float*)d_in[4];
    const float* w_out_s = (const float*)d_in[5];
    const float* b_out_s = (const float*)d_in[6];
    const float* g_out_s = (const float*)d_in[7];
    const float* be_out_s= (const float*)d_in[8];
    const float* w_ff_s  = (const float*)d_in[9];
    const float* b_ff_s  = (const float*)d_in[10];
    const float* g_ff_s  = (const float*)d_in[11];
    const float* be_ff_s = (const float*)d_in[12];
    const float* w_in_t  = (const float*)d_in[13];
    const float* b_in_t  = (const float*)d_in[14];
    const float* alphat_f= (const float*)d_in[15];
    const float* alphat_b= (const float*)d_in[16];
    const float* w_out_t = (const float*)d_in[17];
    const float* b_out_t = (const float*)d_in[18];
    const float* g_out_t = (const float*)d_in[19];
    const float* be_out_t= (const float*)d_in[20];
    const float* w_ff_t  = (const float*)d_in[21];
    const float* b_ff_t  = (const float*)d_in[22];
    const float* g_ff_t  = (const float*)d_in[23];
    const float* be_ff_t = (const float*)d_in[24];
    const float* w_tcn   = (const float*)d_in[25];
    const float* b_tcn   = (const float*)d_in[26];
    const float* g_tcn   = (const float*)d_in[27];
    const float* be_tcn  = (const float*)d_in[28];

    float* ws   = (float*)d_ws;
    float* qk   = ws + OFF_QK;
    float* y2   = ws + OFF_Y2;
    float* xbar = ws + OFF_XBAR;
    float* qkt  = ws + OFF_QKT;
    float* attb = ws + OFF_ATTB;
    float* w2   = ws + OFF_W2;
    float* sout = ws + OFF_SOUT;
    float* atts = ws + OFF_ATTS;
    float* sacc = ws + OFF_SACC;   // -> tmp -> tout
    float* s1   = ws + OFF_S1;     // -> tacc -> t1 (in-place)
    float* out  = (float*)d_out;

    dim3 blk(256);
    const long SV = 409600;        // n-stride for [n][128][3200] buffers
    const float* NUL = nullptr;

    // ---- spatial branch ----
    gemm_k<0,0><<<dim3(2*50, Nn), blk, 0, stream>>>(
        w_in_s, x, qk, NUL, NUL, b_in_s, NUL, NUL,
        192, 128, 128, 3200, 3200, 0, SV, (long)192*3200, 50);
    k_att_s<<<Nn*HSs*Tt, blk, 0, stream>>>(qk, att0s, alphas, atts);
    for (int s = 0; s < HSs; ++s) {
        k_eins<<<Nn*Tt, blk, 0, stream>>>(x, atts, s, y2);
        gemm_k<0,0><<<dim3(50, Nn), blk, 0, stream>>>(
            w_out_s + s*Cc, y2, (s == 2) ? s1 : sacc,
            (s > 0) ? sacc : NUL, (s == 2) ? x : NUL,
            (s == 0) ? b_out_s : NUL,
            (s == 2) ? g_out_s : NUL, be_out_s,
            128, 128, 384, 3200, 3200, 0, SV, SV, 50);
    }
    gemm_k<0,0><<<dim3(50, Nn), blk, 0, stream>>>(
        w_ff_s, s1, sout, NUL, x, b_ff_s, g_ff_s, be_ff_s,
        128, 128, 128, 3200, 3200, 0, SV, SV, 50);

    // ---- temporal branch ----
    k_mean_v<<<(Nn*Cc*Tt + 255)/256, blk, 0, stream>>>(sout, xbar);
    gemm_k<0,0><<<dim3(2*2, Nn), blk, 0, stream>>>(
        w_in_t, xbar, qkt, NUL, NUL, b_in_t, NUL, NUL,
        256, 128, 128, 128, 128, 0, (long)Cc*Tt, (long)256*Tt, 2);
    k_att_t<<<Nn*4, blk, 0, stream>>>(qkt, alphat_f, alphat_b, attb);
    for (int h = 0; h < 4; ++h) {
        // tmp = W_h @ sout
        gemm_k<0,0><<<dim3(50, Nn), blk, 0, stream>>>(
            w_out_t + h*Cc, sout, sacc, NUL, NUL, NUL, NUL, NUL,
            128, 128, 512, 3200, 3200, 0, SV, SV, 50);
        // tacc (+)= att_h applied over t ; last head: t1 = lrelu(sout + bn(tacc))
        gemm_k<3,2><<<dim3(50, Nn), blk, 0, stream>>>(
            attb + (size_t)h*Tt*Tt, sacc, s1,
            (h > 0) ? s1 : NUL, (h == 3) ? sout : NUL,
            (h == 0) ? b_out_t : NUL,
            (h == 3) ? g_out_t : NUL, be_out_t,
            128, 128, 128, 0, 0, (long)4*Tt*Tt, SV, SV, 50);
    }
    // tout = lrelu(sout + bn(W_ff_t @ t1 + b))  -> sacc region
    gemm_k<0,0><<<dim3(50, Nn), blk, 0, stream>>>(
        w_ff_t, s1, sacc, NUL, sout, b_ff_t, g_ff_t, be_ff_t,
        128, 128, 128, 3200, 3200, 0, SV, SV, 50);

    // ---- TCN + final ----
    k_wperm<<<(Cc*Cc*7 + 255)/256, blk, 0, stream>>>(w_tcn, w2);
    gemm_k<1,0><<<dim3(50, Nn), blk, 0, stream>>>(
        w2, sacc, out, NUL, sacc, b_tcn, g_tcn, be_tcn,
        128, 896, 896, 3200, 3200, 0, SV, SV, 50);
}

// Round 6
// 822.907 us; speedup vs baseline: 7.5882x; 1.3640x over previous
//
#include <hip/hip_runtime.h>
#include <cstddef>

#define Nn 32
#define Cc 128
#define Tt 128
#define Vv 25
#define BN_INV 0.9999950000374997f

// ---------------- workspace layout (float offsets), max 53,192,000 ----------
// WB (bf16 weights)    @ 0          (159,744 f as sh)
// QKBF  [n][192][3200] @ 200,000    (9,830,400)   dead after att_s
// S1BF  [n][128][3200] @ 200,000    (reuse, qk dead)
// ATSB  [n][3][t][625] @ 10,030,400 (3,840,000)
// Y2BF  [n][384][3200] @ 13,870,400 (19,660,800)
// SOUT  fp32           @ 33,531,200 (13,107,200)  live til TCN
// ATTB  [n][u][512]    @ 200,000    (reuse, s1 dead)
// XBARB                @ 1,300,000
// QKT   fp32           @ 1,600,000  (1,048,576)
// TMPB  [n][512][3200] @ 2,700,000  (26,214,400)  dead after t1 GEMM
// T1BF  [n][128][3200] @ 46,638,400 (6,553,600)
// TOUT  fp32           @ 2,700,000  (13,107,200, tmp dead)
// TOUTB                @ 15,810,000 (6,553,600)
// NOTE: launches 2+ must see identical ws state as launch 1 -> memset at top
// of kernel_launch (stale-ws dependence caused the R5 post-timing divergence).

typedef __attribute__((ext_vector_type(8))) short bf16x8;
typedef __attribute__((ext_vector_type(4))) float f32x4;

__device__ __forceinline__ unsigned short f2bf(float f) {
    union { float f; unsigned u; } x; x.f = f;
    return (unsigned short)((x.u + 0x7FFFu + ((x.u >> 16) & 1u)) >> 16);
}
__device__ __forceinline__ float bf2f(unsigned short s) {
    union { unsigned u; float f; } x; x.u = ((unsigned)s) << 16;
    return x.f;
}

// =====================================================================
// MFMA bf16 GEMM, tile 128x128, 256 thr = 4 waves, K-block 32.
// A: bf16 row-major [M][lda] @ A + n*an_stride
// BMODE 0: bf16 row-major [K][ldb]
// BMODE 4: fp32 row-major [K][ldb] (convert in loader)
// BMODE 1: TCN shifted: k=(kidx,c): B[k][col] = Bn[c*3200 + col + (kidx-3)*25]
// BMODE 3: tein: k=(h,t), col=(o,v): B[k][col] = Bn[h*409600 + o*3200 + t*25 + v]
// DMODE 0: addr = m*ldd + col ; DMODE 2: m=u, col=(c,v): addr = c*3200+u*25+v
// OM: 0 fp32 D only, 1 bf16 Dbf only, 2 both
// epilogue: val = acc (+bias); if(gg): val = val*g*BN_INV + bb + resp; lrelu
// =====================================================================
template<int BMODE, int DMODE, int OM>
__global__ __launch_bounds__(256, 2) void gemm_k(
    const unsigned short* __restrict__ A, const void* __restrict__ Bv,
    float* __restrict__ D, unsigned short* __restrict__ Dbf,
    const float* __restrict__ resp, const float* __restrict__ bias,
    const float* __restrict__ gg, const float* __restrict__ bb,
    int M, int K, int lda, int ldb, int ldd,
    long an_stride, long bn_stride, long dn_stride, int gn)
{
    __shared__ short Al[8*64*8];   // 8 m-frags x 64 lane-slots x 8 bf16
    __shared__ short Bl[8*64*8];   // 8 col-frags x 64 lane-slots x 8 bf16

    const int n  = blockIdx.y;
    const int mt = blockIdx.x / gn;
    const int nt = blockIdx.x - mt*gn;
    const int m0 = mt*128;
    const int j0 = nt*128;

    const unsigned short* An = A + (size_t)n*an_stride;

    const int tid = threadIdx.x;
    const int wav = tid >> 6, lane = tid & 63;
    const int lq = lane >> 4, l16 = lane & 15;

    const int sm  = tid >> 1, skh = tid & 1;      // A staging: row, k-half
    const int scol = tid & 127, skq = tid >> 7;   // B staging: col, k-half
    const int bcol = j0 + scol;

    int bo = 0, bv_ = 0;
    if (BMODE == 3) { bo = bcol/25; bv_ = bcol - 25*bo; }

    f32x4 acc[2][8];
    #pragma unroll
    for (int i = 0; i < 2; ++i)
        #pragma unroll
        for (int c = 0; c < 8; ++c) acc[i][c] = (f32x4){0.f,0.f,0.f,0.f};

    for (int k0 = 0; k0 < K; k0 += 32) {
        // ---- A fetch: 16 bf16, row m0+sm, k = k0+skh*16 .. +15 ----
        bf16x8 a0 = (bf16x8){0,0,0,0,0,0,0,0}, a1 = a0;
        {
            int mg = m0 + sm;
            if (mg < M) {
                const unsigned short* ap = An + (size_t)mg*lda + k0 + skh*16;
                a0 = *(const bf16x8*)ap;
                a1 = *(const bf16x8*)(ap + 8);
            }
        }
        // ---- B fetch: 16 elems, col bcol, k = k0+skq*16+j ----
        unsigned short bq[16];
        if (BMODE == 0) {
            const unsigned short* Bn = (const unsigned short*)Bv + (size_t)n*bn_stride;
            #pragma unroll
            for (int j = 0; j < 16; ++j)
                bq[j] = Bn[(size_t)(k0 + skq*16 + j)*ldb + bcol];
        } else if (BMODE == 4) {
            const float* Bf = (const float*)Bv + (size_t)n*bn_stride;
            #pragma unroll
            for (int j = 0; j < 16; ++j)
                bq[j] = f2bf(Bf[(size_t)(k0 + skq*16 + j)*ldb + bcol]);
        } else if (BMODE == 1) {
            const unsigned short* Bn = (const unsigned short*)Bv + (size_t)n*bn_stride;
            int kb = k0 + skq*16;
            int kidx = kb >> 7, c0 = kb & 127;
            int e = bcol + (kidx - 3)*25;
            bool ok = ((unsigned)e < 3200u);
            #pragma unroll
            for (int j = 0; j < 16; ++j)
                bq[j] = ok ? Bn[(size_t)(c0 + j)*3200 + e] : (unsigned short)0;
        } else { // BMODE 3
            const unsigned short* Bn = (const unsigned short*)Bv + (size_t)n*bn_stride;
            int kb = k0 + skq*16;
            int h = kb >> 7, t0 = kb & 127;
            const unsigned short* bp = Bn + (size_t)h*409600 + (size_t)bo*3200
                                          + (size_t)t0*25 + bv_;
            #pragma unroll
            for (int j = 0; j < 16; ++j) bq[j] = bp[j*25];
        }

        __syncthreads();   // previous tile consumed
        {
            short* Ap = Al + ((size_t)((sm>>4)*64 + (sm&15) + 32*skh))*8;
            *(bf16x8*)Ap = a0;
            *(bf16x8*)(Ap + 128) = a1;       // +16 lane-slots
        }
        {
            short* Bp = Bl + ((size_t)((scol>>4)*64 + (scol&15) + 32*skq))*8;
            bf16x8 p0, p1;
            #pragma unroll
            for (int j = 0; j < 8; ++j) { p0[j] = (short)bq[j]; p1[j] = (short)bq[8+j]; }
            *(bf16x8*)Bp = p0;
            *(bf16x8*)(Bp + 128) = p1;
        }
        __syncthreads();

        bf16x8 afr[2], bfr[8];
        afr[0] = *(const bf16x8*)(Al + ((size_t)((2*wav+0)*64 + lane))*8);
        afr[1] = *(const bf16x8*)(Al + ((size_t)((2*wav+1)*64 + lane))*8);
        #pragma unroll
        for (int c = 0; c < 8; ++c)
            bfr[c] = *(const bf16x8*)(Bl + ((size_t)(c*64 + lane))*8);
        #pragma unroll
        for (int i = 0; i < 2; ++i)
            #pragma unroll
            for (int c = 0; c < 8; ++c)
                acc[i][c] = __builtin_amdgcn_mfma_f32_16x16x32_bf16(
                    afr[i], bfr[c], acc[i][c], 0, 0, 0);
    }

    // ---- epilogue: row = m0+(2w+i)*16+lq*4+r ; col = j0+ct*16+l16 ----
    #pragma unroll
    for (int i = 0; i < 2; ++i) {
        const int mbase = m0 + (2*wav + i)*16 + lq*4;
        #pragma unroll
        for (int ct = 0; ct < 8; ++ct) {
            const int col = j0 + ct*16 + l16;
            if (DMODE == 0) {
                #pragma unroll
                for (int r = 0; r < 4; ++r) {
                    const int mg = mbase + r;
                    if (mg < M) {
                        const size_t addr = (size_t)mg*ldd + col + (size_t)n*dn_stride;
                        float val = acc[i][ct][r] + (bias ? bias[mg] : 0.f);
                        if (gg) {
                            val = val*(gg[mg]*BN_INV) + bb[mg] + resp[addr];
                            val = val > 0.f ? val : 0.1f*val;
                        }
                        if (OM != 1) D[addr] = val;
                        if (OM >= 1) Dbf[addr] = f2bf(val);
                    }
                }
            } else { // DMODE 2
                const int c = col/25, v = col - 25*c;
                const float bi = bias ? bias[c] : 0.f;
                float gv = 0.f, b2 = 0.f;
                if (gg) { gv = gg[c]*BN_INV; b2 = bb[c]; }
                #pragma unroll
                for (int r = 0; r < 4; ++r) {
                    const int u = mbase + r;
                    const size_t addr = (size_t)c*3200 + (size_t)u*25 + v
                                      + (size_t)n*dn_stride;
                    float val = acc[i][ct][r] + bi;
                    if (gg) {
                        val = val*gv + b2 + resp[addr];
                        val = val > 0.f ? val : 0.1f*val;
                    }
                    if (OM != 1) D[addr] = val;
                    if (OM >= 1) Dbf[addr] = f2bf(val);
                }
            }
        }
    }
}

// weight prep: convert (and permute) all weights to bf16 in WB
__global__ void k_prep(const float* __restrict__ wis, const float* __restrict__ wos,
                       const float* __restrict__ wfs, const float* __restrict__ wit,
                       const float* __restrict__ wot, const float* __restrict__ wft,
                       const float* __restrict__ wtc, unsigned short* __restrict__ W) {
    int i = blockIdx.x*256 + threadIdx.x;
    if (i < 24576) { W[i] = f2bf(wis[i]); return; }          i -= 24576;
    if (i < 49152) { W[24576 + i] = f2bf(wos[i]); return; }  i -= 49152;
    if (i < 16384) { W[73728 + i] = f2bf(wfs[i]); return; }  i -= 16384;
    if (i < 32768) { W[90112 + i] = f2bf(wit[i]); return; }  i -= 32768;
    if (i < 65536) { // [(h*128+o)][c] <- wot[o][h*128+c]
        int ho = i >> 7, c = i & 127; int h = ho >> 7, o = ho & 127;
        W[122880 + i] = f2bf(wot[o*512 + h*128 + c]); return; } i -= 65536;
    if (i < 16384) { W[188416 + i] = f2bf(wft[i]); return; } i -= 16384;
    if (i < 114688) { // [o][kidx*128+c] <- wtc[(o*128+c)*7 + kidx]
        int o = i / 896; int r = i - o*896; int kidx = r >> 7, c = r & 127;
        W[204800 + i] = f2bf(wtc[(o*128 + c)*7 + kidx]); }
}

// spatial attention: atts_bf = att0 + tanh(q.k/32)*alpha  (reads bf16 qk)
__global__ void k_att_s(const unsigned short* __restrict__ qk,
                        const float* __restrict__ att0,
                        const float* __restrict__ alphas,
                        unsigned short* __restrict__ att) {
    int b = blockIdx.x;
    int n = b / (3*Tt); int rem = b - n*(3*Tt); int s = rem / Tt; int t = rem - s*Tt;
    __shared__ float qs[32*Vv], ks[32*Vv];
    const unsigned short* qp = qk + (size_t)n*614400 + (size_t)(s*32)*3200 + t*25;
    const unsigned short* kp = qk + (size_t)n*614400 + (size_t)(96 + s*32)*3200 + t*25;
    for (int i = threadIdx.x; i < 32*Vv; i += 256) {
        int c = i / Vv, v = i - c*Vv;
        qs[i] = bf2f(qp[(size_t)c*3200 + v]);
        ks[i] = bf2f(kp[(size_t)c*3200 + v]);
    }
    __syncthreads();
    float alpha = alphas[s];
    for (int i = threadIdx.x; i < Vv*Vv; i += 256) {
        int u = i / Vv, v = i - u*Vv;
        float a = 0.f;
        #pragma unroll
        for (int c = 0; c < 32; ++c) a += qs[c*Vv + u] * ks[c*Vv + v];
        att[(size_t)n*240000 + (size_t)s*80000 + (size_t)t*625 + i] =
            f2bf(att0[s*625 + i] + tanhf(a * (1.f/32.f)) * alpha);
    }
}

// fused 3-head spatial einsum: y2_bf[(s*128+c)][t*25+v] = sum_u x[c,t,u]*att[s,t,u,v]
__global__ void k_eins(const float* __restrict__ X,
                       const unsigned short* __restrict__ att,
                       unsigned short* __restrict__ y2) {
    int n = blockIdx.x / Tt, t = blockIdx.x % Tt;
    __shared__ float Xs[Cc*Vv];      // [c][u]
    __shared__ float At[3*Vv*Vv];    // [s][v][u]
    const float* xp = X + ((size_t)n*Cc*Tt + t)*Vv;
    for (int i = threadIdx.x; i < Cc*Vv; i += 256) {
        int c = i / Vv, u = i - c*Vv;
        Xs[i] = xp[(size_t)c*3200 + u];
    }
    const unsigned short* ap = att + (size_t)n*240000 + (size_t)t*625;
    for (int i = threadIdx.x; i < 3*625; i += 256) {
        int s = i / 625; int uv = i - s*625; int u = uv/25, v = uv - 25*u;
        At[s*625 + v*25 + u] = bf2f(ap[(size_t)s*80000 + uv]);
    }
    __syncthreads();
    for (int s = 0; s < 3; ++s) {
        for (int i = threadIdx.x; i < 800; i += 256) {
            int cg = i & 31, v = i >> 5;
            const float* xq = Xs + cg*4*Vv;
            const float* aq = At + s*625 + v*25;
            float a0=0,a1=0,a2=0,a3=0;
            #pragma unroll
            for (int u = 0; u < Vv; ++u) {
                float avv = aq[u];
                a0 += xq[u]*avv; a1 += xq[25+u]*avv;
                a2 += xq[50+u]*avv; a3 += xq[75+u]*avv;
            }
            unsigned short* yp = y2 + (size_t)n*1228800
                               + (size_t)(s*128 + cg*4)*3200 + t*25 + v;
            yp[0] = f2bf(a0); yp[3200] = f2bf(a1);
            yp[6400] = f2bf(a2); yp[9600] = f2bf(a3);
        }
    }
}

// xbar_bf[n*16384 + c*128 + t] = mean_v sout
__global__ void k_mean(const float* __restrict__ X, unsigned short* __restrict__ xb) {
    int idx = blockIdx.x*256 + threadIdx.x;
    if (idx >= Nn*Cc*Tt) return;
    const float* p = X + (size_t)idx*25;
    float s = 0.f;
    #pragma unroll
    for (int v = 0; v < Vv; ++v) s += p[v];
    xb[idx] = f2bf(s * (1.f/25.f));
}

// temporal attention: attb_bf[n][u][(h*128+t)] = mask*alpha*tanh(dot/32)
__global__ void k_att_t(const float* __restrict__ qkt, const float* __restrict__ af,
                        const float* __restrict__ ab, unsigned short* __restrict__ attb) {
    int n = blockIdx.x >> 2, h = blockIdx.x & 3;
    __shared__ float qs[32*Tt], ks[32*Tt];
    const float* qp = qkt + (size_t)n*32768 + (size_t)(h*32)*128;
    const float* kp = qkt + (size_t)n*32768 + (size_t)(128 + h*32)*128;
    for (int i = threadIdx.x; i < 32*Tt; i += 256) { qs[i] = qp[i]; ks[i] = kp[i]; }
    __syncthreads();
    float alpha = (h < 2) ? af[h] : ab[h-2];
    for (int i = threadIdx.x; i < Tt*Tt; i += 256) {
        int u = i >> 7, t = i & 127;
        bool keep = (h < 2) ? (t >= u) : (t <= u);
        float val = 0.f;
        if (keep) {
            float a = 0.f;
            #pragma unroll
            for (int c = 0; c < 32; ++c) a += qs[c*Tt + t] * ks[c*Tt + u];
            val = tanhf(a * (1.f/32.f)) * alpha;
        }
        attb[(size_t)n*65536 + (size_t)u*512 + h*128 + t] = f2bf(val);
    }
}

extern "C" void kernel_launch(void* const* d_in, const int* in_sizes, int n_in,
                              void* d_out, int out_size, void* d_ws, size_t ws_size,
                              hipStream_t stream) {
    const float* x       = (const float*)d_in[0];
    const float* w_in_s  = (const float*)d_in[1];
    const float* b_in_s  = (const float*)d_in[2];
    const float* att0s   = (const float*)d_in[3];
    const float* alphas  = (const float*)d_in[4];
    const float* w_out_s = (const float*)d_in[5];
    const float* b_out_s = (const float*)d_in[6];
    const float* g_out_s = (const float*)d_in[7];
    const float* be_out_s= (const float*)d_in[8];
    const float* w_ff_s  = (const float*)d_in[9];
    const float* b_ff_s  = (const float*)d_in[10];
    const float* g_ff_s  = (const float*)d_in[11];
    const float* be_ff_s = (const float*)d_in[12];
    const float* w_in_t  = (const float*)d_in[13];
    const float* b_in_t  = (const float*)d_in[14];
    const float* alphat_f= (const float*)d_in[15];
    const float* alphat_b= (const float*)d_in[16];
    const float* w_out_t = (const float*)d_in[17];
    const float* b_out_t = (const float*)d_in[18];
    const float* g_out_t = (const float*)d_in[19];
    const float* be_out_t= (const float*)d_in[20];
    const float* w_ff_t  = (const float*)d_in[21];
    const float* b_ff_t  = (const float*)d_in[22];
    const float* g_ff_t  = (const float*)d_in[23];
    const float* be_ff_t = (const float*)d_in[24];
    const float* w_tcn   = (const float*)d_in[25];
    const float* b_tcn   = (const float*)d_in[26];
    const float* g_tcn   = (const float*)d_in[27];
    const float* be_tcn  = (const float*)d_in[28];

    // make every launch's workspace state identical to launch 1 (stale-ws
    // dependence caused R5's post-timing divergence). ~35us at blit BW.
    hipMemsetAsync(d_ws, 0, ws_size, stream);

    float* ws = (float*)d_ws;
    unsigned short* WB    = (unsigned short*)ws;
    unsigned short* QKBF  = (unsigned short*)(ws + 200000);
    unsigned short* S1BF  = (unsigned short*)(ws + 200000);
    unsigned short* ATSB  = (unsigned short*)(ws + 10030400);
    unsigned short* Y2BF  = (unsigned short*)(ws + 13870400);
    float*          SOUT  = ws + 33531200;
    unsigned short* ATTB  = (unsigned short*)(ws + 200000);
    unsigned short* XBARB = (unsigned short*)(ws + 1300000);
    float*          QKT   = ws + 1600000;
    unsigned short* TMPB  = (unsigned short*)(ws + 2700000);
    unsigned short* T1BF  = (unsigned short*)(ws + 46638400);
    float*          TOUT  = ws + 2700000;
    unsigned short* TOUTB = (unsigned short*)(ws + 15810000);
    float* out = (float*)d_out;

    unsigned short* wbis = WB;
    unsigned short* wbos = WB + 24576;
    unsigned short* wbfs = WB + 73728;
    unsigned short* wbit = WB + 90112;
    unsigned short* wbot = WB + 122880;
    unsigned short* wbft = WB + 188416;
    unsigned short* wbtc = WB + 204800;

    dim3 blk(256);
    const float* NUL = nullptr;

    k_prep<<<1248, blk, 0, stream>>>(w_in_s, w_out_s, w_ff_s, w_in_t,
                                     w_out_t, w_ff_t, w_tcn, WB);

    // ---- spatial ----
    // qk_bf = W_in_s @ x + b      (M=192, K=128, B fp32)
    gemm_k<4,0,1><<<dim3(50,32), blk, 0, stream>>>(
        wbis, x, nullptr, QKBF, NUL, b_in_s, NUL, NUL,
        192, 128, 128, 3200, 3200, 0L, 409600L, 614400L, 25);
    k_att_s<<<Nn*3*Tt, blk, 0, stream>>>(QKBF, att0s, alphas, ATSB);
    k_eins<<<Nn*Tt, blk, 0, stream>>>(x, ATSB, Y2BF);
    // s1_bf = lrelu(x + bn(W_out_s @ y2 + b))   (K=384 fused over heads)
    gemm_k<0,0,1><<<dim3(25,32), blk, 0, stream>>>(
        wbos, Y2BF, nullptr, S1BF, x, b_out_s, g_out_s, be_out_s,
        128, 384, 384, 3200, 3200, 0L, 1228800L, 409600L, 25);
    // sout = lrelu(x + bn(W_ff_s @ s1 + b))
    gemm_k<0,0,0><<<dim3(25,32), blk, 0, stream>>>(
        wbfs, S1BF, SOUT, nullptr, x, b_ff_s, g_ff_s, be_ff_s,
        128, 128, 128, 3200, 3200, 0L, 409600L, 409600L, 25);

    // ---- temporal ----
    k_mean<<<2048, blk, 0, stream>>>(SOUT, XBARB);
    // qkt = W_in_t @ xbar + b     (M=256, K=128, N=128)
    gemm_k<0,0,0><<<dim3(2,32), blk, 0, stream>>>(
        wbit, XBARB, QKT, nullptr, NUL, b_in_t, NUL, NUL,
        256, 128, 128, 128, 128, 0L, 16384L, 32768L, 1);
    k_att_t<<<Nn*4, blk, 0, stream>>>(QKT, alphat_f, alphat_b, ATTB);
    // tmp_bf[(h,o)] = W_out_t_perm @ sout   (M=512, B fp32)
    gemm_k<4,0,1><<<dim3(100,32), blk, 0, stream>>>(
        wbot, SOUT, nullptr, TMPB, NUL, NUL, NUL, NUL,
        512, 128, 128, 3200, 3200, 0L, 409600L, 1638400L, 25);
    // t1_bf = lrelu(sout + bn(att @ tmp + b))  (K=512 fused over heads, DMODE2)
    gemm_k<3,2,1><<<dim3(25,32), blk, 0, stream>>>(
        ATTB, TMPB, nullptr, T1BF, SOUT, b_out_t, g_out_t, be_out_t,
        128, 512, 512, 3200, 3200, 65536L, 1638400L, 409600L, 25);
    // tout(+bf) = lrelu(sout + bn(W_ff_t @ t1 + b))
    gemm_k<0,0,2><<<dim3(25,32), blk, 0, stream>>>(
        wbft, T1BF, TOUT, TOUTB, SOUT, b_ff_t, g_ff_t, be_ff_t,
        128, 128, 128, 3200, 3200, 0L, 409600L, 409600L, 25);

    // ---- TCN ----
    // out = lrelu(tout + bn(conv7(tout) + b))   (K=896, shifted bf16 B)
    gemm_k<1,0,0><<<dim3(25,32), blk, 0, stream>>>(
        wbtc, TOUTB, out, nullptr, TOUT, b_tcn, g_tcn, be_tcn,
        128, 896, 896, 3200, 3200, 0L, 409600L, 409600L, 25);
}